// Round 4
// baseline (136.295 us; speedup 1.0000x reference)
//
#include <hip/hip_runtime.h>

// Fully fused mag -> ISTFT -> STFT -> phase -> ISTFT.
// N_FFT=16, HOP=4, PAD=8. B=32, K=9 bins, T=65536 frames, LW=262140.
// Interior blocks: 4 frames per lane (two frame-pairs L/H), running the
// validated v2f pipeline twice, cross-linked at halo points. DPP only for
// cross-lane halves; same-lane halves are register references. 16B mag
// loads (dwordx4), 64B/lane dense contiguous nt stores, zero LDS/barriers.
// 2 edge blocks per batch run the validated LDS pipeline.
//
// R1: __shfl +/-1 -> v_mov_b32_dpp WF_SL1/WF_SR1 (neutral; kept).
// R2: LDS 31752 B; occupancy push (small; kept).
// R3: XCD-chunked swizzle + early edge dispatch + nt stores (-1.4us; kept).
// R4: pair-split 4-frames/lane: 2x halo amortization, dwordx4 loads,
//     dense 64B stores, half the waves. launch_bounds(256,3).

#define KB    9
#define TFR   65536
#define LW    262140

#define C1f 0.9238795325112867f
#define C2f 0.7071067811865476f
#define C3f 0.3826834323650898f

#define W1 0.03806023374435663f
#define W2 0.14644660940672627f
#define W3 0.30865828381745514f
#define W4 0.5f
#define W5 0.6913417161825449f
#define W6 0.8535533905932737f
#define W7 0.9619397662556434f

// interior coverage: out frames [256, 65280); 240 frames per wave
#define TMIN   256
#define TMAX   65280
#define FPW    240
#define NWAVES 271            // ceil(65024/240)
#define BXI    68             // ceil(271/4) interior blocks per batch
#define GX     (BXI + 2)      // 70 blocks per batch
#define NBLK   (GX * 32)      // 2240 = 8 * 280 exactly

// edge tiles
#define TILE  1024
#define NW    1048
#define NCA   265
#define NFB   259
#define MSTR  265
#define FSTR  17
#define FSTEP (FSTR - 4)      // OLA j-step

typedef float v2f __attribute__((ext_vector_type(2)));
typedef float v4f __attribute__((ext_vector_type(4)));

static __device__ __forceinline__ v2f mk(float a, float b){ v2f r; r.x=a; r.y=b; return r; }
static __device__ __forceinline__ v2f sp(float c){ v2f r; r.x=c; r.y=c; return r; }
static __device__ __forceinline__ v2f vfma(v2f a, v2f b, v2f c){ return __builtin_elementwise_fma(a,b,c); }
static __device__ __forceinline__ v2f vfma(float a, v2f b, v2f c){ return __builtin_elementwise_fma(sp(a),b,c); }

// DPP wavefront shifts: WF_SL1=0x130 -> lane i reads lane i+1,
// WF_SR1=0x138 -> lane i reads lane i-1. bound_ctrl=0 + old=src: boundary
// lanes keep own value (their outputs are masked off).
static __device__ __forceinline__ float SHP(float x){  // from lane+1
  int xi = __builtin_bit_cast(int, x);
  int r = __builtin_amdgcn_update_dpp(xi, xi, 0x130, 0xF, 0xF, false);
  return __builtin_bit_cast(float, r);
}
static __device__ __forceinline__ float SHM(float x){  // from lane-1
  int xi = __builtin_bit_cast(int, x);
  int r = __builtin_amdgcn_update_dpp(xi, xi, 0x138, 0xF, 0xF, false);
  return __builtin_bit_cast(float, r);
}

static __device__ __forceinline__ void phase1(float m, float Sr, float Si,
                                              float& pr, float& pi){
  float r2 = fmaf(Sr,Sr, Si*Si);
  if (r2 > 0.f) {
    float rin = __builtin_amdgcn_rsqf(r2);
    float mr = m * rin;
    pr = mr * Sr; pi = mr * Si;
  } else { pr = m; pi = 0.f; }
}
static __device__ __forceinline__ void phasev(v2f m, v2f Sr, v2f Si, v2f& pr, v2f& pi){
  float prx, pix, pry, piy;
  phase1(m.x, Sr.x, Si.x, prx, pix);
  phase1(m.y, Sr.y, Si.y, pry, piy);
  pr = mk(prx, pry); pi = mk(pix, piy);
}

// ---- validated v2f pipeline stages (math verbatim; neighbors as params) ----

static __device__ __forceinline__ void stage_a(
    v2f R0, v2f R1, v2f R2, v2f R3, v2f R4, v2f R5, v2f R6, v2f R7, v2f R8,
    v2f& f1, v2f& f2, v2f& f3, v2f& f4, v2f& f5, v2f& f6, v2f& f7, v2f& f8)
{
  v2f p1=R1+R7, m1=R1-R7, p2=R2+R6, m2=R2-R6, p3=R3+R5, m3=R3-R5;
  v2f tp=R0+R8, tm=R0-R8, d13=p1-p3;
  v2f E1 = vfma(2.f, vfma(C1f,m1, vfma(C2f,m2, sp(C3f)*m3)), tm);
  v2f E2 = vfma(2.f, vfma(C2f,d13, -R4), tp);
  v2f E3 = vfma(2.f, vfma(C3f,m1, vfma(-C2f,m2, sp(-C1f)*m3)), tm);
  v2f E4 = vfma(2.f, R4-p2, tp);
  v2f E5 = vfma(2.f, vfma(-C3f,m1, vfma(-C2f,m2, sp(C1f)*m3)), tm);
  v2f E6 = vfma(-2.f, vfma(C2f,d13, R4), tp);
  v2f E7 = vfma(2.f, vfma(-C1f,m1, vfma(C2f,m2, sp(-C3f)*m3)), tm);
  v2f E8 = vfma(2.f, ((p2+R4)-(p1+p3)), tp);
  f1=sp(W1)*E1; f2=sp(W2)*E2; f3=sp(W3)*E3; f4=sp(W4)*E4;
  f5=sp(W5)*E5; f6=sp(W6)*E6; f7=sp(W7)*E7; f8=E8;
}

static __device__ __forceinline__ void stage_a2(
    v2f f1, v2f f2, v2f f3, v2f f4, v2f f5, v2f f6, v2f f7, v2f f8,
    float s4, float s5, float s6, float s7,
    float a1x, float a1y, float a2x, float a2y, float a3x, float a3y,
    float m1y, float m2y, float m3y, float m4y,
    v2f& wc0, v2f& wc1, v2f& wc2, v2f& wc3)
{
  v2f f4p1 = mk(f4.y, s4), f5p1 = mk(f5.y, s5), f6p1 = mk(f6.y, s6), f7p1 = mk(f7.y, s7);
  v2f f1p2 = mk(a1x, a1y), f2p2 = mk(a2x, a2y), f3p2 = mk(a3x, a3y);
  v2f f1m1 = mk(m1y, f1.x), f2m1 = mk(m2y, f2.x), f3m1 = mk(m3y, f3.x), f4m1 = mk(m4y, f4.x);
  const v2f inv24 = sp(1.f/24.f);
  wc0 = (f4p1 + f8 + f4m1) * inv24;
  wc1 = (f1p2 + f5p1 + f7 + f3m1) * inv24;
  wc2 = (f2p2 + f6p1 + f6 + f2m1) * inv24;
  wc3 = (f3p2 + f7p1 + f5 + f1m1) * inv24;
}

static __device__ __forceinline__ void stage_bg(
    v2f wc0, v2f wc1, v2f wc2, v2f wc3,
    float aw0y, float aw1x, float aw1y, float aw2x, float aw2y, float aw3x, float aw3y,
    float pw0x, float pw1x, float pw2x, float pw3x,
    v2f& x1, v2f& x2, v2f& x3, v2f& x4, v2f& x5, v2f& x6, v2f& x7, v2f& x8w,
    v2f& x9, v2f& x10, v2f& x11, v2f& x12, v2f& x13, v2f& x14, v2f& x15)
{
  x1  = mk(aw1x, aw1y); x2  = mk(aw2x, aw2y); x3  = mk(aw3x, aw3y);
  x4  = mk(aw0y, wc0.x); x5 = mk(aw1y, wc1.x); x6 = mk(aw2y, wc2.x); x7 = mk(aw3y, wc3.x);
  x8w = wc0; x9 = wc1; x10 = wc2; x11 = wc3;
  x12 = mk(wc0.y, pw0x); x13 = mk(wc1.y, pw1x); x14 = mk(wc2.y, pw2x); x15 = mk(wc3.y, pw3x);
}

static __device__ __forceinline__ void middle(
    v2f x1, v2f x2, v2f x3, v2f x4, v2f x5, v2f x6, v2f x7, v2f x8w,
    v2f x9, v2f x10, v2f x11, v2f x12, v2f x13, v2f x14, v2f x15,
    v2f R0, v2f R1, v2f R2, v2f R3, v2f R4, v2f R5, v2f R6, v2f R7, v2f R8,
    v2f& fc1, v2f& fc2, v2f& fc3, v2f& fc4, v2f& fc5, v2f& fc6, v2f& fc7, v2f& fc8,
    v2f& fc9, v2f& fc10, v2f& fc11, v2f& fc12, v2f& fc13, v2f& fc14, v2f& fc15)
{
  // window (w0=0 kills tap 0; w8=1)
  x1=sp(W1)*x1; x2=sp(W2)*x2; x3=sp(W3)*x3; x4=sp(W4)*x4; x5=sp(W5)*x5;
  x6=sp(W6)*x6; x7=sp(W7)*x7; x9=sp(W7)*x9; x10=sp(W6)*x10; x11=sp(W5)*x11;
  x12=sp(W4)*x12; x13=sp(W3)*x13; x14=sp(W2)*x14; x15=sp(W1)*x15;

  v2f u1=x1+x15, vv1=x1-x15, u2=x2+x14, vv2=x2-x14, u3=x3+x13, vv3=x3-x13,
      u4=x4+x12, vv4=x4-x12, u5=x5+x11, vv5=x5-x11, u6=x6+x10, vv6=x6-x10,
      u7=x7+x9,  vv7=x7-x9;
  v2f P1=u1+u7, M1=u1-u7, P2=u2+u6, M2=u2-u6, P3=u3+u5, M3=u3-u5;
  v2f D13 = P1-P3;
  v2f Sr0 = x8w + ((P1+P2)+(P3+u4));
  v2f Sr1 = vfma(C1f,M1, vfma(C2f,M2, sp(C3f)*M3)) - x8w;
  v2f Sr2 = vfma(C2f,D13, x8w - u4);
  v2f Sr3 = vfma(C3f,M1, vfma(-C2f,M2, sp(-C1f)*M3)) - x8w;
  v2f Sr4 = (u4 - P2) + x8w;
  v2f Sr5 = vfma(-C3f,M1, vfma(-C2f,M2, sp(C1f)*M3)) - x8w;
  v2f Sr6 = vfma(-C2f,D13, x8w - u4);
  v2f Sr7 = vfma(-C1f,M1, vfma(C2f,M2, sp(-C3f)*M3)) - x8w;
  v2f Sr8 = x8w + ((P2+u4)-(P1+P3));
  v2f Q1=vv1+vv7, N1=vv1-vv7, Q2=vv2+vv6, N2=vv2-vv6, Q3=vv3+vv5, N3=vv3-vv5;
  v2f NN = N1+N3;
  v2f Si1 = -(vfma(C3f,Q1, vfma(C2f,Q2, sp(C1f)*Q3)) + vv4);
  v2f Si2 = -vfma(C2f,NN, N2);
  v2f Si3 = -(vfma(C1f,Q1, vfma(C2f,Q2, sp(-C3f)*Q3)) - vv4);
  v2f Si4 = N3 - N1;
  v2f Si5 = -(vfma(C1f,Q1, vfma(-C2f,Q2, sp(-C3f)*Q3)) + vv4);
  v2f Si6 = vfma(-C2f,NN, N2);
  v2f Si7 = -(vfma(C3f,Q1, vfma(-C2f,Q2, sp(C1f)*Q3)) - vv4);

  // phase recombine
  v2f pr0,pr1,pr2,pr3,pr4,pr5,pr6,pr7,pr8;
  v2f pi1,pi2,pi3,pi4,pi5,pi6,pi7;
  pr0 = mk((Sr0.x >= 0.f) ? R0.x : -R0.x,
           (Sr0.y >= 0.f) ? R0.y : -R0.y);
  phasev(R1, Sr1, Si1, pr1, pi1);
  phasev(R2, Sr2, Si2, pr2, pi2);
  phasev(R3, Sr3, Si3, pr3, pi3);
  phasev(R4, Sr4, Si4, pr4, pi4);
  phasev(R5, Sr5, Si5, pr5, pi5);
  phasev(R6, Sr6, Si6, pr6, pi6);
  phasev(R7, Sr7, Si7, pr7, pi7);
  pr8 = mk((Sr8.x >= 0.f) ? R8.x : -R8.x,
           (Sr8.y >= 0.f) ? R8.y : -R8.y);

  // irfft16 of (pr + i*pi), windowed
  v2f ap1=pr1+pr7, bm1=pr1-pr7, ap2=pr2+pr6, bm2=pr2-pr6, ap3=pr3+pr5, bm3=pr3-pr5;
  v2f tp=pr0+pr8, tm=pr0-pr8, ed=ap1-ap3;
  v2f E1 = vfma(2.f, vfma(C1f,bm1, vfma(C2f,bm2, sp(C3f)*bm3)), tm);
  v2f E2 = vfma(2.f, vfma(C2f,ed, -pr4), tp);
  v2f E3 = vfma(2.f, vfma(C3f,bm1, vfma(-C2f,bm2, sp(-C1f)*bm3)), tm);
  v2f E4 = vfma(2.f, pr4-ap2, tp);
  v2f E5 = vfma(2.f, vfma(-C3f,bm1, vfma(-C2f,bm2, sp(C1f)*bm3)), tm);
  v2f E6 = vfma(-2.f, vfma(C2f,ed, pr4), tp);
  v2f E7 = vfma(2.f, vfma(-C1f,bm1, vfma(C2f,bm2, sp(-C3f)*bm3)), tm);
  v2f E8 = vfma(2.f, ((ap2+pr4)-(ap1+ap3)), tp);
  v2f q1=pi1+pi7, n1=pi1-pi7, q2=pi2+pi6, n2=pi2-pi6, q3=pi3+pi5, n3=pi3-pi5;
  v2f nn = n1+n3;
  v2f O1 = sp(-2.f)*(vfma(C3f,q1, vfma(C2f,q2, sp(C1f)*q3)) + pi4);
  v2f O2 = sp(-2.f)*vfma(C2f,nn, n2);
  v2f O3 = sp(-2.f)*(vfma(C1f,q1, vfma(C2f,q2, sp(-C3f)*q3)) - pi4);
  v2f O4 = sp(-2.f)*(n1-n3);
  v2f O5 = sp(-2.f)*(vfma(C1f,q1, vfma(-C2f,q2, sp(-C3f)*q3)) + pi4);
  v2f O6 = sp(-2.f)*vfma(C2f,nn, -n2);
  v2f O7 = sp(-2.f)*(vfma(C3f,q1, vfma(-C2f,q2, sp(C1f)*q3)) - pi4);

  fc1 = sp(W1)*(E1+O1); fc2 = sp(W2)*(E2+O2); fc3 = sp(W3)*(E3+O3); fc4 = sp(W4)*(E4+O4);
  fc5 = sp(W5)*(E5+O5); fc6 = sp(W6)*(E6+O6); fc7 = sp(W7)*(E7+O7); fc8 = E8;
  fc9  = sp(W7)*(E7-O7); fc10 = sp(W6)*(E6-O6); fc11 = sp(W5)*(E5-O5); fc12 = sp(W4)*(E4-O4);
  fc13 = sp(W3)*(E3-O3); fc14 = sp(W2)*(E2-O2); fc15 = sp(W1)*(E1-O1);
}

static __device__ __forceinline__ void stage_c(
    v2f fc4, v2f fc5, v2f fc6, v2f fc7, v2f fc8, v2f fc9, v2f fc10, v2f fc11,
    v2f fc12, v2f fc13, v2f fc14, v2f fc15,
    float c1x, float c1y, float c2x, float c2y, float c3x, float c3y,
    float c4x, float c5x, float c6x, float c7x,
    float d12, float d13s, float d14, float d15,
    v2f& o0, v2f& o1, v2f& o2, v2f& o3)
{
  v2f g1 = mk(c1x, c1y), g2 = mk(c2x, c2y), g3 = mk(c3x, c3y);
  v2f h4 = mk(fc4.y, c4x), h5 = mk(fc5.y, c5x), h6 = mk(fc6.y, c6x), h7 = mk(fc7.y, c7x);
  v2f q12 = mk(d12, fc12.x), q13 = mk(d13s, fc13.x), q14 = mk(d14, fc14.x), q15 = mk(d15, fc15.x);
  const v2f inv24 = sp(1.f/24.f);
  o0 = (h4 + fc8  + q12) * inv24;
  o1 = (g1 + h5 + fc9  + q13) * inv24;
  o2 = (g2 + h6 + fc10 + q14) * inv24;
  o3 = (g3 + h7 + fc11 + q15) * inv24;
}

__device__ __constant__ float W2C[16] = {
  0.f, W1*W1, W2*W2, W3*W3, 0.25f, W5*W5, W6*W6, W7*W7,
  1.f, W7*W7, W6*W6, W5*W5, 0.25f, W3*W3, W2*W2, W1*W1 };

__global__ __launch_bounds__(256, 3) void istft_all(
    const float* __restrict__ mag, float* __restrict__ out)
{
  // edge-path LDS (unused by interior blocks). 31752 B.
  __shared__ float s_mag[KB * MSTR];
  __shared__ float s_fab[NCA * FSTR];
  __shared__ float s_wav[NW];

  const int tid = threadIdx.x;

  // XCD-chunked bijective swizzle: 2240 = 8 * 280.
  const unsigned lin = (unsigned)blockIdx.y * GX + blockIdx.x;  // 0..2239
  const unsigned swz = (lin & 7u) * (NBLK / 8u) + (lin >> 3);   // bijective
  const unsigned b   = swz / (unsigned)GX;                      // batch
  const int      pos = (int)(swz - b * GX);                     // 0..69

  const float* magb = mag + (size_t)b * (size_t)(KB * TFR);
  float* outb = out + (size_t)b * LW;

  if (pos >= 2) {
    // ------- interior: 1 lane = 4 frames (pairs L,H), DPP + reg halo -------
    const int lane = tid & 63;
    const int wv   = (pos - 2) * 4 + (tid >> 6);
    if (wv >= NWAVES) return;
    const int T0 = TMIN + wv * FPW;
    const int tb = T0 - 8 + 4 * lane;       // 4-aligned; frames tb..tb+3

    // mag columns tb..tb+3 for 9 bins: dwordx4 loads, 16B/lane
    const float* mp = magb + tb;
    v4f Q0 = *(const v4f*)(mp + 0*TFR);
    v4f Q1 = *(const v4f*)(mp + 1*TFR);
    v4f Q2 = *(const v4f*)(mp + 2*TFR);
    v4f Q3 = *(const v4f*)(mp + 3*TFR);
    v4f Q4 = *(const v4f*)(mp + 4*TFR);
    v4f Q5 = *(const v4f*)(mp + 5*TFR);
    v4f Q6 = *(const v4f*)(mp + 6*TFR);
    v4f Q7 = *(const v4f*)(mp + 7*TFR);
    v4f Q8 = *(const v4f*)(mp + 8*TFR);
    v2f RL0 = mk(Q0.x,Q0.y), RH0 = mk(Q0.z,Q0.w);
    v2f RL1 = mk(Q1.x,Q1.y), RH1 = mk(Q1.z,Q1.w);
    v2f RL2 = mk(Q2.x,Q2.y), RH2 = mk(Q2.z,Q2.w);
    v2f RL3 = mk(Q3.x,Q3.y), RH3 = mk(Q3.z,Q3.w);
    v2f RL4 = mk(Q4.x,Q4.y), RH4 = mk(Q4.z,Q4.w);
    v2f RL5 = mk(Q5.x,Q5.y), RH5 = mk(Q5.z,Q5.w);
    v2f RL6 = mk(Q6.x,Q6.y), RH6 = mk(Q6.z,Q6.w);
    v2f RL7 = mk(Q7.x,Q7.y), RH7 = mk(Q7.z,Q7.w);
    v2f RL8 = mk(Q8.x,Q8.y), RH8 = mk(Q8.z,Q8.w);

    // ---- stage A (pure, both pairs) ----
    v2f fL1,fL2,fL3,fL4,fL5,fL6,fL7,fL8;
    v2f fH1,fH2,fH3,fH4,fH5,fH6,fH7,fH8;
    stage_a(RL0,RL1,RL2,RL3,RL4,RL5,RL6,RL7,RL8, fL1,fL2,fL3,fL4,fL5,fL6,fL7,fL8);
    stage_a(RH0,RH1,RH2,RH3,RH4,RH5,RH6,RH7,RH8, fH1,fH2,fH3,fH4,fH5,fH6,fH7,fH8);

    // ---- stage A2: L's next = same-lane H (free); L's prev = (lane-1).H ----
    //                H's next = (lane+1).L;       H's prev = same-lane L (free)
    v2f wcL0,wcL1,wcL2,wcL3, wcH0,wcH1,wcH2,wcH3;
    stage_a2(fL1,fL2,fL3,fL4,fL5,fL6,fL7,fL8,
             fH4.x, fH5.x, fH6.x, fH7.x,
             fH1.x, fH1.y, fH2.x, fH2.y, fH3.x, fH3.y,
             SHM(fH1.y), SHM(fH2.y), SHM(fH3.y), SHM(fH4.y),
             wcL0,wcL1,wcL2,wcL3);
    stage_a2(fH1,fH2,fH3,fH4,fH5,fH6,fH7,fH8,
             SHP(fL4.x), SHP(fL5.x), SHP(fL6.x), SHP(fL7.x),
             SHP(fL1.x), SHP(fL1.y), SHP(fL2.x), SHP(fL2.y), SHP(fL3.x), SHP(fL3.y),
             fL1.y, fL2.y, fL3.y, fL4.y,
             wcH0,wcH1,wcH2,wcH3);

    // ---- stage B gather ----
    v2f xL1,xL2,xL3,xL4,xL5,xL6,xL7,xL8w,xL9,xL10,xL11,xL12,xL13,xL14,xL15;
    v2f xH1,xH2,xH3,xH4,xH5,xH6,xH7,xH8w,xH9,xH10,xH11,xH12,xH13,xH14,xH15;
    stage_bg(wcL0,wcL1,wcL2,wcL3,
             SHM(wcH0.y), SHM(wcH1.x), SHM(wcH1.y), SHM(wcH2.x), SHM(wcH2.y), SHM(wcH3.x), SHM(wcH3.y),
             wcH0.x, wcH1.x, wcH2.x, wcH3.x,
             xL1,xL2,xL3,xL4,xL5,xL6,xL7,xL8w,xL9,xL10,xL11,xL12,xL13,xL14,xL15);
    stage_bg(wcH0,wcH1,wcH2,wcH3,
             wcL0.y, wcL1.x, wcL1.y, wcL2.x, wcL2.y, wcL3.x, wcL3.y,
             SHP(wcL0.x), SHP(wcL1.x), SHP(wcL2.x), SHP(wcL3.x),
             xH1,xH2,xH3,xH4,xH5,xH6,xH7,xH8w,xH9,xH10,xH11,xH12,xH13,xH14,xH15);

    // ---- middle: window -> STFT -> phase -> irfft (pure, both pairs) ----
    v2f fcL1,fcL2,fcL3,fcL4,fcL5,fcL6,fcL7,fcL8,fcL9,fcL10,fcL11,fcL12,fcL13,fcL14,fcL15;
    v2f fcH1,fcH2,fcH3,fcH4,fcH5,fcH6,fcH7,fcH8,fcH9,fcH10,fcH11,fcH12,fcH13,fcH14,fcH15;
    middle(xL1,xL2,xL3,xL4,xL5,xL6,xL7,xL8w,xL9,xL10,xL11,xL12,xL13,xL14,xL15,
           RL0,RL1,RL2,RL3,RL4,RL5,RL6,RL7,RL8,
           fcL1,fcL2,fcL3,fcL4,fcL5,fcL6,fcL7,fcL8,fcL9,fcL10,fcL11,fcL12,fcL13,fcL14,fcL15);
    middle(xH1,xH2,xH3,xH4,xH5,xH6,xH7,xH8w,xH9,xH10,xH11,xH12,xH13,xH14,xH15,
           RH0,RH1,RH2,RH3,RH4,RH5,RH6,RH7,RH8,
           fcH1,fcH2,fcH3,fcH4,fcH5,fcH6,fcH7,fcH8,fcH9,fcH10,fcH11,fcH12,fcH13,fcH14,fcH15);

    // ---- stage C: final OLA ----
    v2f oL0,oL1,oL2,oL3, oH0,oH1,oH2,oH3;
    stage_c(fcL4,fcL5,fcL6,fcL7,fcL8,fcL9,fcL10,fcL11,fcL12,fcL13,fcL14,fcL15,
            fcH1.x, fcH1.y, fcH2.x, fcH2.y, fcH3.x, fcH3.y,
            fcH4.x, fcH5.x, fcH6.x, fcH7.x,
            SHM(fcH12.y), SHM(fcH13.y), SHM(fcH14.y), SHM(fcH15.y),
            oL0,oL1,oL2,oL3);
    stage_c(fcH4,fcH5,fcH6,fcH7,fcH8,fcH9,fcH10,fcH11,fcH12,fcH13,fcH14,fcH15,
            SHP(fcL1.x), SHP(fcL1.y), SHP(fcL2.x), SHP(fcL2.y), SHP(fcL3.x), SHP(fcL3.y),
            SHP(fcL4.x), SHP(fcL5.x), SHP(fcL6.x), SHP(fcL7.x),
            fcL12.y, fcL13.y, fcL14.y, fcL15.y,
            oH0,oH1,oH2,oH3);

    // frames tb..tb+3 -> out[4tb .. 4tb+15], 64B dense per lane
    if (lane >= 2 && lane <= 61 && tb < TMAX) {
      v4f s0 = {oL0.x,oL1.x,oL2.x,oL3.x};
      v4f s1 = {oL0.y,oL1.y,oL2.y,oL3.y};
      v4f s2 = {oH0.x,oH1.x,oH2.x,oH3.x};
      v4f s3 = {oH0.y,oH1.y,oH2.y,oH3.y};
      float* op = outb + 4*(size_t)tb;
      __builtin_nontemporal_store(s0, (v4f*)op);
      __builtin_nontemporal_store(s1, (v4f*)(op+4));
      __builtin_nontemporal_store(s2, (v4f*)(op+8));
      __builtin_nontemporal_store(s3, (v4f*)(op+12));
    }
    return;
  }

  // ---------------- edge blocks: validated LDS pipeline ----------------
  const int l0  = (pos == 0) ? 0 : 261120;
  const int t4  = l0 >> 2;
  const int tAlo = t4 - 4;
  const int tBlo = t4 - 1;
  const int wbase = l0 - 12;

#pragma unroll
  for (int k = 0; k < KB; ++k) {
    const float* mrow = magb + (size_t)k * TFR + tAlo;
    for (int c = tid; c < NCA; c += 256) {
      int t = tAlo + c;
      s_mag[k * MSTR + c] = ((unsigned)t < (unsigned)TFR) ? mrow[c] : 0.f;
    }
  }
  __syncthreads();

  for (int f = tid; f < NCA; f += 256) {
    float R0 = s_mag[0*MSTR+f], R1 = s_mag[1*MSTR+f], R2 = s_mag[2*MSTR+f],
          R3 = s_mag[3*MSTR+f], R4 = s_mag[4*MSTR+f], R5 = s_mag[5*MSTR+f],
          R6 = s_mag[6*MSTR+f], R7 = s_mag[7*MSTR+f], R8 = s_mag[8*MSTR+f];
    float p1=R1+R7, m1=R1-R7, p2=R2+R6, m2=R2-R6, p3=R3+R5, m3=R3-R5;
    float tp=R0+R8, tm=R0-R8, d13=p1-p3;
    float E1 = fmaf(2.f, fmaf(C1f,m1, fmaf(C2f,m2, C3f*m3)), tm);
    float E2 = fmaf(2.f, fmaf(C2f,d13, -R4), tp);
    float E3 = fmaf(2.f, fmaf(C3f,m1, fmaf(-C2f,m2, -C1f*m3)), tm);
    float E4 = fmaf(2.f, R4-p2, tp);
    float E5 = fmaf(2.f, fmaf(-C3f,m1, fmaf(-C2f,m2, C1f*m3)), tm);
    float E6 = fmaf(-2.f, fmaf(C2f,d13, R4), tp);
    float E7 = fmaf(2.f, fmaf(-C1f,m1, fmaf(C2f,m2, -C3f*m3)), tm);
    float E8 = fmaf(2.f, ((p2+R4)-(p1+p3)), tp);
    float* rp = s_fab + f * FSTR;
    rp[0]=0.f;    rp[1]=W1*E1;  rp[2]=W2*E2;  rp[3]=W3*E3;
    rp[4]=W4*E4;  rp[5]=W5*E5;  rp[6]=W6*E6;  rp[7]=W7*E7;
    rp[8]=E8;     rp[9]=W7*E7;  rp[10]=W6*E6; rp[11]=W5*E5;
    rp[12]=W4*E4; rp[13]=W3*E3; rp[14]=W2*E2; rp[15]=W1*E1;
  }
  __syncthreads();

  for (int i = tid; i < NW; i += 256) {
    int m = wbase + i;
    float val = 0.f;
    if (m >= 0 && m < LW) {
      int q = m + 8;
      int tq = q >> 2, r = q & 3;
      int base = (tq - tAlo) * FSTR + r;
      float acc = 0.f, env = 0.f;
#pragma unroll
      for (int j = 0; j < 4; ++j) {
        int t = tq - j;
        if ((unsigned)t < (unsigned)TFR) { acc += s_fab[base - FSTEP*j]; env += W2C[r + 4*j]; }
      }
      val = acc * __builtin_amdgcn_rcpf(16.f * env);
    }
    s_wav[i] = val;
  }
  __syncthreads();

  for (int f = tid; f < NFB; f += 256) {
    float* rp = s_fab + f * FSTR;
    int t2 = tBlo + f;
    bool valid = ((unsigned)t2 < (unsigned)TFR);
    if (valid) {
      float xs[16];
      int g0 = 4*t2 - 8;
#pragma unroll
      for (int n = 0; n < 16; ++n) {
        int g = g0 + n;
        g = (g < 0) ? -g : g;
        g = (g < LW) ? g : (2*(LW-1) - g);
        xs[n] = s_wav[g - wbase];
      }
      float x1=xs[1]*W1, x2=xs[2]*W2, x3=xs[3]*W3, x4=xs[4]*W4, x5=xs[5]*W5,
            x6=xs[6]*W6, x7=xs[7]*W7, x8w=xs[8], x9=xs[9]*W7, x10=xs[10]*W6,
            x11=xs[11]*W5, x12=xs[12]*W4, x13=xs[13]*W3, x14=xs[14]*W2, x15=xs[15]*W1;
      float u1=x1+x15, v1=x1-x15, u2=x2+x14, v2=x2-x14, u3=x3+x13, v3=x3-x13,
            u4=x4+x12, v4=x4-x12, u5=x5+x11, v5=x5-x11, u6=x6+x10, v6=x6-x10,
            u7=x7+x9,  v7=x7-x9;
      float P1=u1+u7, M1=u1-u7, P2=u2+u6, M2=u2-u6, P3=u3+u5, M3=u3-u5;
      float D13 = P1-P3;
      float Sr0 = x8w + ((P1+P2)+(P3+u4));
      float Sr1 = fmaf(C1f,M1, fmaf(C2f,M2, C3f*M3)) - x8w;
      float Sr2 = fmaf(C2f,D13, x8w - u4);
      float Sr3 = fmaf(C3f,M1, fmaf(-C2f,M2, -C1f*M3)) - x8w;
      float Sr4 = (u4 - P2) + x8w;
      float Sr5 = fmaf(-C3f,M1, fmaf(-C2f,M2, C1f*M3)) - x8w;
      float Sr6 = fmaf(-C2f,D13, x8w - u4);
      float Sr7 = fmaf(-C1f,M1, fmaf(C2f,M2, -C3f*M3)) - x8w;
      float Sr8 = x8w + ((P2+u4)-(P1+P3));
      float Q1=v1+v7, N1=v1-v7, Q2=v2+v6, N2=v2-v6, Q3=v3+v5, N3=v3-v5;
      float NN = N1+N3;
      float Si1 = -(fmaf(C3f,Q1, fmaf(C2f,Q2, C1f*Q3)) + v4);
      float Si2 = -fmaf(C2f,NN, N2);
      float Si3 = -(fmaf(C1f,Q1, fmaf(C2f,Q2, -C3f*Q3)) - v4);
      float Si4 = N3 - N1;
      float Si5 = -(fmaf(C1f,Q1, fmaf(-C2f,Q2, -C3f*Q3)) + v4);
      float Si6 = fmaf(-C2f,NN, N2);
      float Si7 = -(fmaf(C3f,Q1, fmaf(-C2f,Q2, C1f*Q3)) - v4);

      const float* mcol = s_mag + (f + 3);
      float pr0,pr1,pr2,pr3,pr4,pr5,pr6,pr7,pr8;
      float pi1,pi2,pi3,pi4,pi5,pi6,pi7;
      { float mm = mcol[0];
        pr0 = (Sr0 >= 0.f) ? mm : -mm; }
      phase1(mcol[1*MSTR], Sr1, Si1, pr1, pi1);
      phase1(mcol[2*MSTR], Sr2, Si2, pr2, pi2);
      phase1(mcol[3*MSTR], Sr3, Si3, pr3, pi3);
      phase1(mcol[4*MSTR], Sr4, Si4, pr4, pi4);
      phase1(mcol[5*MSTR], Sr5, Si5, pr5, pi5);
      phase1(mcol[6*MSTR], Sr6, Si6, pr6, pi6);
      phase1(mcol[7*MSTR], Sr7, Si7, pr7, pi7);
      { float mm = mcol[8*MSTR];
        pr8 = (Sr8 >= 0.f) ? mm : -mm; }

      float ap1=pr1+pr7, bm1=pr1-pr7, ap2=pr2+pr6, bm2=pr2-pr6, ap3=pr3+pr5, bm3=pr3-pr5;
      float tp=pr0+pr8, tm=pr0-pr8, ed=ap1-ap3;
      float E1 = fmaf(2.f, fmaf(C1f,bm1, fmaf(C2f,bm2, C3f*bm3)), tm);
      float E2 = fmaf(2.f, fmaf(C2f,ed, -pr4), tp);
      float E3 = fmaf(2.f, fmaf(C3f,bm1, fmaf(-C2f,bm2, -C1f*bm3)), tm);
      float E4 = fmaf(2.f, pr4-ap2, tp);
      float E5 = fmaf(2.f, fmaf(-C3f,bm1, fmaf(-C2f,bm2, C1f*bm3)), tm);
      float E6 = fmaf(-2.f, fmaf(C2f,ed, pr4), tp);
      float E7 = fmaf(2.f, fmaf(-C1f,bm1, fmaf(C2f,bm2, -C3f*bm3)), tm);
      float E8 = fmaf(2.f, ((ap2+pr4)-(ap1+ap3)), tp);
      float q1=pi1+pi7, n1=pi1-pi7, q2=pi2+pi6, n2=pi2-pi6, q3=pi3+pi5, n3=pi3-pi5;
      float nn = n1+n3;
      float O1 = -2.f*(fmaf(C3f,q1, fmaf(C2f,q2, C1f*q3)) + pi4);
      float O2 = -2.f*fmaf(C2f,nn, n2);
      float O3 = -2.f*(fmaf(C1f,q1, fmaf(C2f,q2, -C3f*q3)) - pi4);
      float O4 = -2.f*(n1-n3);
      float O5 = -2.f*(fmaf(C1f,q1, fmaf(-C2f,q2, -C3f*q3)) + pi4);
      float O6 = -2.f*fmaf(C2f,nn, -n2);
      float O7 = -2.f*(fmaf(C3f,q1, fmaf(-C2f,q2, C1f*q3)) - pi4);

      rp[0]=0.f;          rp[1]=W1*(E1+O1);  rp[2]=W2*(E2+O2);  rp[3]=W3*(E3+O3);
      rp[4]=W4*(E4+O4);   rp[5]=W5*(E5+O5);  rp[6]=W6*(E6+O6);  rp[7]=W7*(E7+O7);
      rp[8]=E8;           rp[9]=W7*(E7-O7);  rp[10]=W6*(E6-O6); rp[11]=W5*(E5-O5);
      rp[12]=W4*(E4-O4);  rp[13]=W3*(E3-O3); rp[14]=W2*(E2-O2); rp[15]=W1*(E1-O1);
    } else {
#pragma unroll
      for (int n = 0; n < 16; ++n) rp[n] = 0.f;
    }
  }
  __syncthreads();

  for (int i = tid; i < TILE; i += 256) {
    int l = l0 + i;
    if (l < LW) {
      int q = l + 8;
      int tq = q >> 2, r = q & 3;
      int base = (tq - tBlo) * FSTR + r;
      float acc = 0.f, env = 0.f;
#pragma unroll
      for (int j = 0; j < 4; ++j) {
        int t = tq - j;
        if ((unsigned)t < (unsigned)TFR) { acc += s_fab[base - FSTEP*j]; env += W2C[r + 4*j]; }
      }
      __builtin_nontemporal_store(acc * __builtin_amdgcn_rcpf(16.f * env), &outb[l]);
    }
  }
}

extern "C" void kernel_launch(void* const* d_in, const int* in_sizes, int n_in,
                              void* d_out, int out_size, void* d_ws, size_t ws_size,
                              hipStream_t stream) {
  const float* mag = (const float*)d_in[0];   // (32, 9, 65536) f32
  float* out = (float*)d_out;                 // (32, 262140) f32
  dim3 grid(GX, 32);                          // 70 blocks/batch (2 edge + 68 interior)
  istft_all<<<grid, 256, 0, stream>>>(mag, out);
}

// Round 5
// 134.075 us; speedup vs baseline: 1.0166x; 1.0166x over previous
//
#include <hip/hip_runtime.h>

// Fully fused mag -> ISTFT -> STFT -> phase -> ISTFT.
// N_FFT=16, HOP=4, PAD=8. B=32, K=9 bins, T=65536 frames, LW=262140.
// Interior blocks: 4 frames per lane (two frame-pairs L/H), running the
// validated v2f pipeline twice, cross-linked at halo points. DPP only for
// cross-lane halves; same-lane halves are register references. 16B mag
// loads (dwordx4), 64B/lane dense contiguous nt stores, zero LDS/barriers.
// 2 edge blocks per batch run the validated LDS pipeline.
//
// R1: __shfl +/-1 -> v_mov_b32_dpp WF_SL1/WF_SR1 (neutral; kept).
// R2: LDS 31752 B; occupancy push (small; kept).
// R3: XCD-chunked swizzle + early edge dispatch + nt stores (-1.4us; kept).
// R4: pair-split 4-frames/lane. REGRESSED via spills: backend targeted
//     8 waves/EU -> 64 VGPR -> WRITE_SIZE 2x (scratch). launch_bounds min
//     waves only sets a register FLOOR, not an occupancy ceiling.
// R5: amdgpu_waves_per_eu(2,3) caps target occupancy -> 170-256 VGPR
//     budget, ~160-reg peak fits spill-free. Code otherwise identical.

#define KB    9
#define TFR   65536
#define LW    262140

#define C1f 0.9238795325112867f
#define C2f 0.7071067811865476f
#define C3f 0.3826834323650898f

#define W1 0.03806023374435663f
#define W2 0.14644660940672627f
#define W3 0.30865828381745514f
#define W4 0.5f
#define W5 0.6913417161825449f
#define W6 0.8535533905932737f
#define W7 0.9619397662556434f

// interior coverage: out frames [256, 65280); 240 frames per wave
#define TMIN   256
#define TMAX   65280
#define FPW    240
#define NWAVES 271            // ceil(65024/240)
#define BXI    68             // ceil(271/4) interior blocks per batch
#define GX     (BXI + 2)      // 70 blocks per batch
#define NBLK   (GX * 32)      // 2240 = 8 * 280 exactly

// edge tiles
#define TILE  1024
#define NW    1048
#define NCA   265
#define NFB   259
#define MSTR  265
#define FSTR  17
#define FSTEP (FSTR - 4)      // OLA j-step

typedef float v2f __attribute__((ext_vector_type(2)));
typedef float v4f __attribute__((ext_vector_type(4)));

static __device__ __forceinline__ v2f mk(float a, float b){ v2f r; r.x=a; r.y=b; return r; }
static __device__ __forceinline__ v2f sp(float c){ v2f r; r.x=c; r.y=c; return r; }
static __device__ __forceinline__ v2f vfma(v2f a, v2f b, v2f c){ return __builtin_elementwise_fma(a,b,c); }
static __device__ __forceinline__ v2f vfma(float a, v2f b, v2f c){ return __builtin_elementwise_fma(sp(a),b,c); }

// DPP wavefront shifts: WF_SL1=0x130 -> lane i reads lane i+1,
// WF_SR1=0x138 -> lane i reads lane i-1. bound_ctrl=0 + old=src: boundary
// lanes keep own value (their outputs are masked off).
static __device__ __forceinline__ float SHP(float x){  // from lane+1
  int xi = __builtin_bit_cast(int, x);
  int r = __builtin_amdgcn_update_dpp(xi, xi, 0x130, 0xF, 0xF, false);
  return __builtin_bit_cast(float, r);
}
static __device__ __forceinline__ float SHM(float x){  // from lane-1
  int xi = __builtin_bit_cast(int, x);
  int r = __builtin_amdgcn_update_dpp(xi, xi, 0x138, 0xF, 0xF, false);
  return __builtin_bit_cast(float, r);
}

static __device__ __forceinline__ void phase1(float m, float Sr, float Si,
                                              float& pr, float& pi){
  float r2 = fmaf(Sr,Sr, Si*Si);
  if (r2 > 0.f) {
    float rin = __builtin_amdgcn_rsqf(r2);
    float mr = m * rin;
    pr = mr * Sr; pi = mr * Si;
  } else { pr = m; pi = 0.f; }
}
static __device__ __forceinline__ void phasev(v2f m, v2f Sr, v2f Si, v2f& pr, v2f& pi){
  float prx, pix, pry, piy;
  phase1(m.x, Sr.x, Si.x, prx, pix);
  phase1(m.y, Sr.y, Si.y, pry, piy);
  pr = mk(prx, pry); pi = mk(pix, piy);
}

// ---- validated v2f pipeline stages (math verbatim; neighbors as params) ----

static __device__ __forceinline__ void stage_a(
    v2f R0, v2f R1, v2f R2, v2f R3, v2f R4, v2f R5, v2f R6, v2f R7, v2f R8,
    v2f& f1, v2f& f2, v2f& f3, v2f& f4, v2f& f5, v2f& f6, v2f& f7, v2f& f8)
{
  v2f p1=R1+R7, m1=R1-R7, p2=R2+R6, m2=R2-R6, p3=R3+R5, m3=R3-R5;
  v2f tp=R0+R8, tm=R0-R8, d13=p1-p3;
  v2f E1 = vfma(2.f, vfma(C1f,m1, vfma(C2f,m2, sp(C3f)*m3)), tm);
  v2f E2 = vfma(2.f, vfma(C2f,d13, -R4), tp);
  v2f E3 = vfma(2.f, vfma(C3f,m1, vfma(-C2f,m2, sp(-C1f)*m3)), tm);
  v2f E4 = vfma(2.f, R4-p2, tp);
  v2f E5 = vfma(2.f, vfma(-C3f,m1, vfma(-C2f,m2, sp(C1f)*m3)), tm);
  v2f E6 = vfma(-2.f, vfma(C2f,d13, R4), tp);
  v2f E7 = vfma(2.f, vfma(-C1f,m1, vfma(C2f,m2, sp(-C3f)*m3)), tm);
  v2f E8 = vfma(2.f, ((p2+R4)-(p1+p3)), tp);
  f1=sp(W1)*E1; f2=sp(W2)*E2; f3=sp(W3)*E3; f4=sp(W4)*E4;
  f5=sp(W5)*E5; f6=sp(W6)*E6; f7=sp(W7)*E7; f8=E8;
}

static __device__ __forceinline__ void stage_a2(
    v2f f1, v2f f2, v2f f3, v2f f4, v2f f5, v2f f6, v2f f7, v2f f8,
    float s4, float s5, float s6, float s7,
    float a1x, float a1y, float a2x, float a2y, float a3x, float a3y,
    float m1y, float m2y, float m3y, float m4y,
    v2f& wc0, v2f& wc1, v2f& wc2, v2f& wc3)
{
  v2f f4p1 = mk(f4.y, s4), f5p1 = mk(f5.y, s5), f6p1 = mk(f6.y, s6), f7p1 = mk(f7.y, s7);
  v2f f1p2 = mk(a1x, a1y), f2p2 = mk(a2x, a2y), f3p2 = mk(a3x, a3y);
  v2f f1m1 = mk(m1y, f1.x), f2m1 = mk(m2y, f2.x), f3m1 = mk(m3y, f3.x), f4m1 = mk(m4y, f4.x);
  const v2f inv24 = sp(1.f/24.f);
  wc0 = (f4p1 + f8 + f4m1) * inv24;
  wc1 = (f1p2 + f5p1 + f7 + f3m1) * inv24;
  wc2 = (f2p2 + f6p1 + f6 + f2m1) * inv24;
  wc3 = (f3p2 + f7p1 + f5 + f1m1) * inv24;
}

static __device__ __forceinline__ void stage_bg(
    v2f wc0, v2f wc1, v2f wc2, v2f wc3,
    float aw0y, float aw1x, float aw1y, float aw2x, float aw2y, float aw3x, float aw3y,
    float pw0x, float pw1x, float pw2x, float pw3x,
    v2f& x1, v2f& x2, v2f& x3, v2f& x4, v2f& x5, v2f& x6, v2f& x7, v2f& x8w,
    v2f& x9, v2f& x10, v2f& x11, v2f& x12, v2f& x13, v2f& x14, v2f& x15)
{
  x1  = mk(aw1x, aw1y); x2  = mk(aw2x, aw2y); x3  = mk(aw3x, aw3y);
  x4  = mk(aw0y, wc0.x); x5 = mk(aw1y, wc1.x); x6 = mk(aw2y, wc2.x); x7 = mk(aw3y, wc3.x);
  x8w = wc0; x9 = wc1; x10 = wc2; x11 = wc3;
  x12 = mk(wc0.y, pw0x); x13 = mk(wc1.y, pw1x); x14 = mk(wc2.y, pw2x); x15 = mk(wc3.y, pw3x);
}

static __device__ __forceinline__ void middle(
    v2f x1, v2f x2, v2f x3, v2f x4, v2f x5, v2f x6, v2f x7, v2f x8w,
    v2f x9, v2f x10, v2f x11, v2f x12, v2f x13, v2f x14, v2f x15,
    v2f R0, v2f R1, v2f R2, v2f R3, v2f R4, v2f R5, v2f R6, v2f R7, v2f R8,
    v2f& fc1, v2f& fc2, v2f& fc3, v2f& fc4, v2f& fc5, v2f& fc6, v2f& fc7, v2f& fc8,
    v2f& fc9, v2f& fc10, v2f& fc11, v2f& fc12, v2f& fc13, v2f& fc14, v2f& fc15)
{
  // window (w0=0 kills tap 0; w8=1)
  x1=sp(W1)*x1; x2=sp(W2)*x2; x3=sp(W3)*x3; x4=sp(W4)*x4; x5=sp(W5)*x5;
  x6=sp(W6)*x6; x7=sp(W7)*x7; x9=sp(W7)*x9; x10=sp(W6)*x10; x11=sp(W5)*x11;
  x12=sp(W4)*x12; x13=sp(W3)*x13; x14=sp(W2)*x14; x15=sp(W1)*x15;

  v2f u1=x1+x15, vv1=x1-x15, u2=x2+x14, vv2=x2-x14, u3=x3+x13, vv3=x3-x13,
      u4=x4+x12, vv4=x4-x12, u5=x5+x11, vv5=x5-x11, u6=x6+x10, vv6=x6-x10,
      u7=x7+x9,  vv7=x7-x9;
  v2f P1=u1+u7, M1=u1-u7, P2=u2+u6, M2=u2-u6, P3=u3+u5, M3=u3-u5;
  v2f D13 = P1-P3;
  v2f Sr0 = x8w + ((P1+P2)+(P3+u4));
  v2f Sr1 = vfma(C1f,M1, vfma(C2f,M2, sp(C3f)*M3)) - x8w;
  v2f Sr2 = vfma(C2f,D13, x8w - u4);
  v2f Sr3 = vfma(C3f,M1, vfma(-C2f,M2, sp(-C1f)*M3)) - x8w;
  v2f Sr4 = (u4 - P2) + x8w;
  v2f Sr5 = vfma(-C3f,M1, vfma(-C2f,M2, sp(C1f)*M3)) - x8w;
  v2f Sr6 = vfma(-C2f,D13, x8w - u4);
  v2f Sr7 = vfma(-C1f,M1, vfma(C2f,M2, sp(-C3f)*M3)) - x8w;
  v2f Sr8 = x8w + ((P2+u4)-(P1+P3));
  v2f Q1=vv1+vv7, N1=vv1-vv7, Q2=vv2+vv6, N2=vv2-vv6, Q3=vv3+vv5, N3=vv3-vv5;
  v2f NN = N1+N3;
  v2f Si1 = -(vfma(C3f,Q1, vfma(C2f,Q2, sp(C1f)*Q3)) + vv4);
  v2f Si2 = -vfma(C2f,NN, N2);
  v2f Si3 = -(vfma(C1f,Q1, vfma(C2f,Q2, sp(-C3f)*Q3)) - vv4);
  v2f Si4 = N3 - N1;
  v2f Si5 = -(vfma(C1f,Q1, vfma(-C2f,Q2, sp(-C3f)*Q3)) + vv4);
  v2f Si6 = vfma(-C2f,NN, N2);
  v2f Si7 = -(vfma(C3f,Q1, vfma(-C2f,Q2, sp(C1f)*Q3)) - vv4);

  // phase recombine
  v2f pr0,pr1,pr2,pr3,pr4,pr5,pr6,pr7,pr8;
  v2f pi1,pi2,pi3,pi4,pi5,pi6,pi7;
  pr0 = mk((Sr0.x >= 0.f) ? R0.x : -R0.x,
           (Sr0.y >= 0.f) ? R0.y : -R0.y);
  phasev(R1, Sr1, Si1, pr1, pi1);
  phasev(R2, Sr2, Si2, pr2, pi2);
  phasev(R3, Sr3, Si3, pr3, pi3);
  phasev(R4, Sr4, Si4, pr4, pi4);
  phasev(R5, Sr5, Si5, pr5, pi5);
  phasev(R6, Sr6, Si6, pr6, pi6);
  phasev(R7, Sr7, Si7, pr7, pi7);
  pr8 = mk((Sr8.x >= 0.f) ? R8.x : -R8.x,
           (Sr8.y >= 0.f) ? R8.y : -R8.y);

  // irfft16 of (pr + i*pi), windowed
  v2f ap1=pr1+pr7, bm1=pr1-pr7, ap2=pr2+pr6, bm2=pr2-pr6, ap3=pr3+pr5, bm3=pr3-pr5;
  v2f tp=pr0+pr8, tm=pr0-pr8, ed=ap1-ap3;
  v2f E1 = vfma(2.f, vfma(C1f,bm1, vfma(C2f,bm2, sp(C3f)*bm3)), tm);
  v2f E2 = vfma(2.f, vfma(C2f,ed, -pr4), tp);
  v2f E3 = vfma(2.f, vfma(C3f,bm1, vfma(-C2f,bm2, sp(-C1f)*bm3)), tm);
  v2f E4 = vfma(2.f, pr4-ap2, tp);
  v2f E5 = vfma(2.f, vfma(-C3f,bm1, vfma(-C2f,bm2, sp(C1f)*bm3)), tm);
  v2f E6 = vfma(-2.f, vfma(C2f,ed, pr4), tp);
  v2f E7 = vfma(2.f, vfma(-C1f,bm1, vfma(C2f,bm2, sp(-C3f)*bm3)), tm);
  v2f E8 = vfma(2.f, ((ap2+pr4)-(ap1+ap3)), tp);
  v2f q1=pi1+pi7, n1=pi1-pi7, q2=pi2+pi6, n2=pi2-pi6, q3=pi3+pi5, n3=pi3-pi5;
  v2f nn = n1+n3;
  v2f O1 = sp(-2.f)*(vfma(C3f,q1, vfma(C2f,q2, sp(C1f)*q3)) + pi4);
  v2f O2 = sp(-2.f)*vfma(C2f,nn, n2);
  v2f O3 = sp(-2.f)*(vfma(C1f,q1, vfma(C2f,q2, sp(-C3f)*q3)) - pi4);
  v2f O4 = sp(-2.f)*(n1-n3);
  v2f O5 = sp(-2.f)*(vfma(C1f,q1, vfma(-C2f,q2, sp(-C3f)*q3)) + pi4);
  v2f O6 = sp(-2.f)*vfma(C2f,nn, -n2);
  v2f O7 = sp(-2.f)*(vfma(C3f,q1, vfma(-C2f,q2, sp(C1f)*q3)) - pi4);

  fc1 = sp(W1)*(E1+O1); fc2 = sp(W2)*(E2+O2); fc3 = sp(W3)*(E3+O3); fc4 = sp(W4)*(E4+O4);
  fc5 = sp(W5)*(E5+O5); fc6 = sp(W6)*(E6+O6); fc7 = sp(W7)*(E7+O7); fc8 = E8;
  fc9  = sp(W7)*(E7-O7); fc10 = sp(W6)*(E6-O6); fc11 = sp(W5)*(E5-O5); fc12 = sp(W4)*(E4-O4);
  fc13 = sp(W3)*(E3-O3); fc14 = sp(W2)*(E2-O2); fc15 = sp(W1)*(E1-O1);
}

static __device__ __forceinline__ void stage_c(
    v2f fc4, v2f fc5, v2f fc6, v2f fc7, v2f fc8, v2f fc9, v2f fc10, v2f fc11,
    v2f fc12, v2f fc13, v2f fc14, v2f fc15,
    float c1x, float c1y, float c2x, float c2y, float c3x, float c3y,
    float c4x, float c5x, float c6x, float c7x,
    float d12, float d13s, float d14, float d15,
    v2f& o0, v2f& o1, v2f& o2, v2f& o3)
{
  v2f g1 = mk(c1x, c1y), g2 = mk(c2x, c2y), g3 = mk(c3x, c3y);
  v2f h4 = mk(fc4.y, c4x), h5 = mk(fc5.y, c5x), h6 = mk(fc6.y, c6x), h7 = mk(fc7.y, c7x);
  v2f q12 = mk(d12, fc12.x), q13 = mk(d13s, fc13.x), q14 = mk(d14, fc14.x), q15 = mk(d15, fc15.x);
  const v2f inv24 = sp(1.f/24.f);
  o0 = (h4 + fc8  + q12) * inv24;
  o1 = (g1 + h5 + fc9  + q13) * inv24;
  o2 = (g2 + h6 + fc10 + q14) * inv24;
  o3 = (g3 + h7 + fc11 + q15) * inv24;
}

__device__ __constant__ float W2C[16] = {
  0.f, W1*W1, W2*W2, W3*W3, 0.25f, W5*W5, W6*W6, W7*W7,
  1.f, W7*W7, W6*W6, W5*W5, 0.25f, W3*W3, W2*W2, W1*W1 };

__global__ __launch_bounds__(256)
__attribute__((amdgpu_waves_per_eu(2, 3)))
void istft_all(
    const float* __restrict__ mag, float* __restrict__ out)
{
  // edge-path LDS (unused by interior blocks). 31752 B.
  __shared__ float s_mag[KB * MSTR];
  __shared__ float s_fab[NCA * FSTR];
  __shared__ float s_wav[NW];

  const int tid = threadIdx.x;

  // XCD-chunked bijective swizzle: 2240 = 8 * 280.
  const unsigned lin = (unsigned)blockIdx.y * GX + blockIdx.x;  // 0..2239
  const unsigned swz = (lin & 7u) * (NBLK / 8u) + (lin >> 3);   // bijective
  const unsigned b   = swz / (unsigned)GX;                      // batch
  const int      pos = (int)(swz - b * GX);                     // 0..69

  const float* magb = mag + (size_t)b * (size_t)(KB * TFR);
  float* outb = out + (size_t)b * LW;

  if (pos >= 2) {
    // ------- interior: 1 lane = 4 frames (pairs L,H), DPP + reg halo -------
    const int lane = tid & 63;
    const int wv   = (pos - 2) * 4 + (tid >> 6);
    if (wv >= NWAVES) return;
    const int T0 = TMIN + wv * FPW;
    const int tb = T0 - 8 + 4 * lane;       // 4-aligned; frames tb..tb+3

    // mag columns tb..tb+3 for 9 bins: dwordx4 loads, 16B/lane
    const float* mp = magb + tb;
    v4f Q0 = *(const v4f*)(mp + 0*TFR);
    v4f Q1 = *(const v4f*)(mp + 1*TFR);
    v4f Q2 = *(const v4f*)(mp + 2*TFR);
    v4f Q3 = *(const v4f*)(mp + 3*TFR);
    v4f Q4 = *(const v4f*)(mp + 4*TFR);
    v4f Q5 = *(const v4f*)(mp + 5*TFR);
    v4f Q6 = *(const v4f*)(mp + 6*TFR);
    v4f Q7 = *(const v4f*)(mp + 7*TFR);
    v4f Q8 = *(const v4f*)(mp + 8*TFR);
    v2f RL0 = mk(Q0.x,Q0.y), RH0 = mk(Q0.z,Q0.w);
    v2f RL1 = mk(Q1.x,Q1.y), RH1 = mk(Q1.z,Q1.w);
    v2f RL2 = mk(Q2.x,Q2.y), RH2 = mk(Q2.z,Q2.w);
    v2f RL3 = mk(Q3.x,Q3.y), RH3 = mk(Q3.z,Q3.w);
    v2f RL4 = mk(Q4.x,Q4.y), RH4 = mk(Q4.z,Q4.w);
    v2f RL5 = mk(Q5.x,Q5.y), RH5 = mk(Q5.z,Q5.w);
    v2f RL6 = mk(Q6.x,Q6.y), RH6 = mk(Q6.z,Q6.w);
    v2f RL7 = mk(Q7.x,Q7.y), RH7 = mk(Q7.z,Q7.w);
    v2f RL8 = mk(Q8.x,Q8.y), RH8 = mk(Q8.z,Q8.w);

    // ---- stage A (pure, both pairs) ----
    v2f fL1,fL2,fL3,fL4,fL5,fL6,fL7,fL8;
    v2f fH1,fH2,fH3,fH4,fH5,fH6,fH7,fH8;
    stage_a(RL0,RL1,RL2,RL3,RL4,RL5,RL6,RL7,RL8, fL1,fL2,fL3,fL4,fL5,fL6,fL7,fL8);
    stage_a(RH0,RH1,RH2,RH3,RH4,RH5,RH6,RH7,RH8, fH1,fH2,fH3,fH4,fH5,fH6,fH7,fH8);

    // ---- stage A2: L's next = same-lane H (free); L's prev = (lane-1).H ----
    //                H's next = (lane+1).L;       H's prev = same-lane L (free)
    v2f wcL0,wcL1,wcL2,wcL3, wcH0,wcH1,wcH2,wcH3;
    stage_a2(fL1,fL2,fL3,fL4,fL5,fL6,fL7,fL8,
             fH4.x, fH5.x, fH6.x, fH7.x,
             fH1.x, fH1.y, fH2.x, fH2.y, fH3.x, fH3.y,
             SHM(fH1.y), SHM(fH2.y), SHM(fH3.y), SHM(fH4.y),
             wcL0,wcL1,wcL2,wcL3);
    stage_a2(fH1,fH2,fH3,fH4,fH5,fH6,fH7,fH8,
             SHP(fL4.x), SHP(fL5.x), SHP(fL6.x), SHP(fL7.x),
             SHP(fL1.x), SHP(fL1.y), SHP(fL2.x), SHP(fL2.y), SHP(fL3.x), SHP(fL3.y),
             fL1.y, fL2.y, fL3.y, fL4.y,
             wcH0,wcH1,wcH2,wcH3);

    // ---- stage B gather ----
    v2f xL1,xL2,xL3,xL4,xL5,xL6,xL7,xL8w,xL9,xL10,xL11,xL12,xL13,xL14,xL15;
    v2f xH1,xH2,xH3,xH4,xH5,xH6,xH7,xH8w,xH9,xH10,xH11,xH12,xH13,xH14,xH15;
    stage_bg(wcL0,wcL1,wcL2,wcL3,
             SHM(wcH0.y), SHM(wcH1.x), SHM(wcH1.y), SHM(wcH2.x), SHM(wcH2.y), SHM(wcH3.x), SHM(wcH3.y),
             wcH0.x, wcH1.x, wcH2.x, wcH3.x,
             xL1,xL2,xL3,xL4,xL5,xL6,xL7,xL8w,xL9,xL10,xL11,xL12,xL13,xL14,xL15);
    stage_bg(wcH0,wcH1,wcH2,wcH3,
             wcL0.y, wcL1.x, wcL1.y, wcL2.x, wcL2.y, wcL3.x, wcL3.y,
             SHP(wcL0.x), SHP(wcL1.x), SHP(wcL2.x), SHP(wcL3.x),
             xH1,xH2,xH3,xH4,xH5,xH6,xH7,xH8w,xH9,xH10,xH11,xH12,xH13,xH14,xH15);

    // ---- middle: window -> STFT -> phase -> irfft (pure, both pairs) ----
    v2f fcL1,fcL2,fcL3,fcL4,fcL5,fcL6,fcL7,fcL8,fcL9,fcL10,fcL11,fcL12,fcL13,fcL14,fcL15;
    v2f fcH1,fcH2,fcH3,fcH4,fcH5,fcH6,fcH7,fcH8,fcH9,fcH10,fcH11,fcH12,fcH13,fcH14,fcH15;
    middle(xL1,xL2,xL3,xL4,xL5,xL6,xL7,xL8w,xL9,xL10,xL11,xL12,xL13,xL14,xL15,
           RL0,RL1,RL2,RL3,RL4,RL5,RL6,RL7,RL8,
           fcL1,fcL2,fcL3,fcL4,fcL5,fcL6,fcL7,fcL8,fcL9,fcL10,fcL11,fcL12,fcL13,fcL14,fcL15);
    middle(xH1,xH2,xH3,xH4,xH5,xH6,xH7,xH8w,xH9,xH10,xH11,xH12,xH13,xH14,xH15,
           RH0,RH1,RH2,RH3,RH4,RH5,RH6,RH7,RH8,
           fcH1,fcH2,fcH3,fcH4,fcH5,fcH6,fcH7,fcH8,fcH9,fcH10,fcH11,fcH12,fcH13,fcH14,fcH15);

    // ---- stage C: final OLA ----
    v2f oL0,oL1,oL2,oL3, oH0,oH1,oH2,oH3;
    stage_c(fcL4,fcL5,fcL6,fcL7,fcL8,fcL9,fcL10,fcL11,fcL12,fcL13,fcL14,fcL15,
            fcH1.x, fcH1.y, fcH2.x, fcH2.y, fcH3.x, fcH3.y,
            fcH4.x, fcH5.x, fcH6.x, fcH7.x,
            SHM(fcH12.y), SHM(fcH13.y), SHM(fcH14.y), SHM(fcH15.y),
            oL0,oL1,oL2,oL3);
    stage_c(fcH4,fcH5,fcH6,fcH7,fcH8,fcH9,fcH10,fcH11,fcH12,fcH13,fcH14,fcH15,
            SHP(fcL1.x), SHP(fcL1.y), SHP(fcL2.x), SHP(fcL2.y), SHP(fcL3.x), SHP(fcL3.y),
            SHP(fcL4.x), SHP(fcL5.x), SHP(fcL6.x), SHP(fcL7.x),
            fcL12.y, fcL13.y, fcL14.y, fcL15.y,
            oH0,oH1,oH2,oH3);

    // frames tb..tb+3 -> out[4tb .. 4tb+15], 64B dense per lane
    if (lane >= 2 && lane <= 61 && tb < TMAX) {
      v4f s0 = {oL0.x,oL1.x,oL2.x,oL3.x};
      v4f s1 = {oL0.y,oL1.y,oL2.y,oL3.y};
      v4f s2 = {oH0.x,oH1.x,oH2.x,oH3.x};
      v4f s3 = {oH0.y,oH1.y,oH2.y,oH3.y};
      float* op = outb + 4*(size_t)tb;
      __builtin_nontemporal_store(s0, (v4f*)op);
      __builtin_nontemporal_store(s1, (v4f*)(op+4));
      __builtin_nontemporal_store(s2, (v4f*)(op+8));
      __builtin_nontemporal_store(s3, (v4f*)(op+12));
    }
    return;
  }

  // ---------------- edge blocks: validated LDS pipeline ----------------
  const int l0  = (pos == 0) ? 0 : 261120;
  const int t4  = l0 >> 2;
  const int tAlo = t4 - 4;
  const int tBlo = t4 - 1;
  const int wbase = l0 - 12;

#pragma unroll
  for (int k = 0; k < KB; ++k) {
    const float* mrow = magb + (size_t)k * TFR + tAlo;
    for (int c = tid; c < NCA; c += 256) {
      int t = tAlo + c;
      s_mag[k * MSTR + c] = ((unsigned)t < (unsigned)TFR) ? mrow[c] : 0.f;
    }
  }
  __syncthreads();

  for (int f = tid; f < NCA; f += 256) {
    float R0 = s_mag[0*MSTR+f], R1 = s_mag[1*MSTR+f], R2 = s_mag[2*MSTR+f],
          R3 = s_mag[3*MSTR+f], R4 = s_mag[4*MSTR+f], R5 = s_mag[5*MSTR+f],
          R6 = s_mag[6*MSTR+f], R7 = s_mag[7*MSTR+f], R8 = s_mag[8*MSTR+f];
    float p1=R1+R7, m1=R1-R7, p2=R2+R6, m2=R2-R6, p3=R3+R5, m3=R3-R5;
    float tp=R0+R8, tm=R0-R8, d13=p1-p3;
    float E1 = fmaf(2.f, fmaf(C1f,m1, fmaf(C2f,m2, C3f*m3)), tm);
    float E2 = fmaf(2.f, fmaf(C2f,d13, -R4), tp);
    float E3 = fmaf(2.f, fmaf(C3f,m1, fmaf(-C2f,m2, -C1f*m3)), tm);
    float E4 = fmaf(2.f, R4-p2, tp);
    float E5 = fmaf(2.f, fmaf(-C3f,m1, fmaf(-C2f,m2, C1f*m3)), tm);
    float E6 = fmaf(-2.f, fmaf(C2f,d13, R4), tp);
    float E7 = fmaf(2.f, fmaf(-C1f,m1, fmaf(C2f,m2, -C3f*m3)), tm);
    float E8 = fmaf(2.f, ((p2+R4)-(p1+p3)), tp);
    float* rp = s_fab + f * FSTR;
    rp[0]=0.f;    rp[1]=W1*E1;  rp[2]=W2*E2;  rp[3]=W3*E3;
    rp[4]=W4*E4;  rp[5]=W5*E5;  rp[6]=W6*E6;  rp[7]=W7*E7;
    rp[8]=E8;     rp[9]=W7*E7;  rp[10]=W6*E6; rp[11]=W5*E5;
    rp[12]=W4*E4; rp[13]=W3*E3; rp[14]=W2*E2; rp[15]=W1*E1;
  }
  __syncthreads();

  for (int i = tid; i < NW; i += 256) {
    int m = wbase + i;
    float val = 0.f;
    if (m >= 0 && m < LW) {
      int q = m + 8;
      int tq = q >> 2, r = q & 3;
      int base = (tq - tAlo) * FSTR + r;
      float acc = 0.f, env = 0.f;
#pragma unroll
      for (int j = 0; j < 4; ++j) {
        int t = tq - j;
        if ((unsigned)t < (unsigned)TFR) { acc += s_fab[base - FSTEP*j]; env += W2C[r + 4*j]; }
      }
      val = acc * __builtin_amdgcn_rcpf(16.f * env);
    }
    s_wav[i] = val;
  }
  __syncthreads();

  for (int f = tid; f < NFB; f += 256) {
    float* rp = s_fab + f * FSTR;
    int t2 = tBlo + f;
    bool valid = ((unsigned)t2 < (unsigned)TFR);
    if (valid) {
      float xs[16];
      int g0 = 4*t2 - 8;
#pragma unroll
      for (int n = 0; n < 16; ++n) {
        int g = g0 + n;
        g = (g < 0) ? -g : g;
        g = (g < LW) ? g : (2*(LW-1) - g);
        xs[n] = s_wav[g - wbase];
      }
      float x1=xs[1]*W1, x2=xs[2]*W2, x3=xs[3]*W3, x4=xs[4]*W4, x5=xs[5]*W5,
            x6=xs[6]*W6, x7=xs[7]*W7, x8w=xs[8], x9=xs[9]*W7, x10=xs[10]*W6,
            x11=xs[11]*W5, x12=xs[12]*W4, x13=xs[13]*W3, x14=xs[14]*W2, x15=xs[15]*W1;
      float u1=x1+x15, v1=x1-x15, u2=x2+x14, v2=x2-x14, u3=x3+x13, v3=x3-x13,
            u4=x4+x12, v4=x4-x12, u5=x5+x11, v5=x5-x11, u6=x6+x10, v6=x6-x10,
            u7=x7+x9,  v7=x7-x9;
      float P1=u1+u7, M1=u1-u7, P2=u2+u6, M2=u2-u6, P3=u3+u5, M3=u3-u5;
      float D13 = P1-P3;
      float Sr0 = x8w + ((P1+P2)+(P3+u4));
      float Sr1 = fmaf(C1f,M1, fmaf(C2f,M2, C3f*M3)) - x8w;
      float Sr2 = fmaf(C2f,D13, x8w - u4);
      float Sr3 = fmaf(C3f,M1, fmaf(-C2f,M2, -C1f*M3)) - x8w;
      float Sr4 = (u4 - P2) + x8w;
      float Sr5 = fmaf(-C3f,M1, fmaf(-C2f,M2, C1f*M3)) - x8w;
      float Sr6 = fmaf(-C2f,D13, x8w - u4);
      float Sr7 = fmaf(-C1f,M1, fmaf(C2f,M2, -C3f*M3)) - x8w;
      float Sr8 = x8w + ((P2+u4)-(P1+P3));
      float Q1=v1+v7, N1=v1-v7, Q2=v2+v6, N2=v2-v6, Q3=v3+v5, N3=v3-v5;
      float NN = N1+N3;
      float Si1 = -(fmaf(C3f,Q1, fmaf(C2f,Q2, C1f*Q3)) + v4);
      float Si2 = -fmaf(C2f,NN, N2);
      float Si3 = -(fmaf(C1f,Q1, fmaf(C2f,Q2, -C3f*Q3)) - v4);
      float Si4 = N3 - N1;
      float Si5 = -(fmaf(C1f,Q1, fmaf(-C2f,Q2, -C3f*Q3)) + v4);
      float Si6 = fmaf(-C2f,NN, N2);
      float Si7 = -(fmaf(C3f,Q1, fmaf(-C2f,Q2, C1f*Q3)) - v4);

      const float* mcol = s_mag + (f + 3);
      float pr0,pr1,pr2,pr3,pr4,pr5,pr6,pr7,pr8;
      float pi1,pi2,pi3,pi4,pi5,pi6,pi7;
      { float mm = mcol[0];
        pr0 = (Sr0 >= 0.f) ? mm : -mm; }
      phase1(mcol[1*MSTR], Sr1, Si1, pr1, pi1);
      phase1(mcol[2*MSTR], Sr2, Si2, pr2, pi2);
      phase1(mcol[3*MSTR], Sr3, Si3, pr3, pi3);
      phase1(mcol[4*MSTR], Sr4, Si4, pr4, pi4);
      phase1(mcol[5*MSTR], Sr5, Si5, pr5, pi5);
      phase1(mcol[6*MSTR], Sr6, Si6, pr6, pi6);
      phase1(mcol[7*MSTR], Sr7, Si7, pr7, pi7);
      { float mm = mcol[8*MSTR];
        pr8 = (Sr8 >= 0.f) ? mm : -mm; }

      float ap1=pr1+pr7, bm1=pr1-pr7, ap2=pr2+pr6, bm2=pr2-pr6, ap3=pr3+pr5, bm3=pr3-pr5;
      float tp=pr0+pr8, tm=pr0-pr8, ed=ap1-ap3;
      float E1 = fmaf(2.f, fmaf(C1f,bm1, fmaf(C2f,bm2, C3f*bm3)), tm);
      float E2 = fmaf(2.f, fmaf(C2f,ed, -pr4), tp);
      float E3 = fmaf(2.f, fmaf(C3f,bm1, fmaf(-C2f,bm2, -C1f*bm3)), tm);
      float E4 = fmaf(2.f, pr4-ap2, tp);
      float E5 = fmaf(2.f, fmaf(-C3f,bm1, fmaf(-C2f,bm2, C1f*bm3)), tm);
      float E6 = fmaf(-2.f, fmaf(C2f,ed, pr4), tp);
      float E7 = fmaf(2.f, fmaf(-C1f,bm1, fmaf(C2f,bm2, -C3f*bm3)), tm);
      float E8 = fmaf(2.f, ((ap2+pr4)-(ap1+ap3)), tp);
      float q1=pi1+pi7, n1=pi1-pi7, q2=pi2+pi6, n2=pi2-pi6, q3=pi3+pi5, n3=pi3-pi5;
      float nn = n1+n3;
      float O1 = -2.f*(fmaf(C3f,q1, fmaf(C2f,q2, C1f*q3)) + pi4);
      float O2 = -2.f*fmaf(C2f,nn, n2);
      float O3 = -2.f*(fmaf(C1f,q1, fmaf(C2f,q2, -C3f*q3)) - pi4);
      float O4 = -2.f*(n1-n3);
      float O5 = -2.f*(fmaf(C1f,q1, fmaf(-C2f,q2, -C3f*q3)) + pi4);
      float O6 = -2.f*fmaf(C2f,nn, -n2);
      float O7 = -2.f*(fmaf(C3f,q1, fmaf(-C2f,q2, C1f*q3)) - pi4);

      rp[0]=0.f;          rp[1]=W1*(E1+O1);  rp[2]=W2*(E2+O2);  rp[3]=W3*(E3+O3);
      rp[4]=W4*(E4+O4);   rp[5]=W5*(E5+O5);  rp[6]=W6*(E6+O6);  rp[7]=W7*(E7+O7);
      rp[8]=E8;           rp[9]=W7*(E7-O7);  rp[10]=W6*(E6-O6); rp[11]=W5*(E5-O5);
      rp[12]=W4*(E4-O4);  rp[13]=W3*(E3-O3); rp[14]=W2*(E2-O2); rp[15]=W1*(E1-O1);
    } else {
#pragma unroll
      for (int n = 0; n < 16; ++n) rp[n] = 0.f;
    }
  }
  __syncthreads();

  for (int i = tid; i < TILE; i += 256) {
    int l = l0 + i;
    if (l < LW) {
      int q = l + 8;
      int tq = q >> 2, r = q & 3;
      int base = (tq - tBlo) * FSTR + r;
      float acc = 0.f, env = 0.f;
#pragma unroll
      for (int j = 0; j < 4; ++j) {
        int t = tq - j;
        if ((unsigned)t < (unsigned)TFR) { acc += s_fab[base - FSTEP*j]; env += W2C[r + 4*j]; }
      }
      __builtin_nontemporal_store(acc * __builtin_amdgcn_rcpf(16.f * env), &outb[l]);
    }
  }
}

extern "C" void kernel_launch(void* const* d_in, const int* in_sizes, int n_in,
                              void* d_out, int out_size, void* d_ws, size_t ws_size,
                              hipStream_t stream) {
  const float* mag = (const float*)d_in[0];   // (32, 9, 65536) f32
  float* out = (float*)d_out;                 // (32, 262140) f32
  dim3 grid(GX, 32);                          // 70 blocks/batch (2 edge + 68 interior)
  istft_all<<<grid, 256, 0, stream>>>(mag, out);
}

// Round 6
// 119.846 us; speedup vs baseline: 1.1372x; 1.1187x over previous
//
#include <hip/hip_runtime.h>

// Fully fused mag -> ISTFT -> STFT -> phase -> ISTFT.
// N_FFT=16, HOP=4, PAD=8. B=32, K=9 bins, T=65536 frames, LW=262140.
// Single kernel: interior blocks use wave-shuffle pipeline with 2 frames
// per lane (packed-f32 math, DPP wavefront-shift halo exchange, zero
// LDS/barriers); 2 edge blocks per batch run the validated LDS pipeline for
// the first and last 1024 samples (reflect-pad + partial-env cases).
//
// R1: __shfl +/-1 -> v_mov_b32_dpp WF_SL1/WF_SR1 (neutral; kept).
// R2: LDS 35040->31752 B + 5 waves/SIMD occupancy (+1us; kept).
// R3: XCD-chunked swizzle + early edge dispatch + nt stores (-1.4us; kept).
//     == THIS KERNEL (121.7us harness-verified) ==
// R4/R5: pair-split 4-frames/lane FALSIFIED: AMDGPU backend pins 64-68
//     VGPR (occupancy heuristic) despite launch_bounds(256,3) and
//     amdgpu_waves_per_eu(2,3); ~160-reg live front spills to scratch
//     (WRITE_SIZE 2x, +20us). Not fixable at HIP source level. Reverted.

#define KB    9
#define TFR   65536
#define LW    262140

#define C1f 0.9238795325112867f
#define C2f 0.7071067811865476f
#define C3f 0.3826834323650898f

#define W1 0.03806023374435663f
#define W2 0.14644660940672627f
#define W3 0.30865828381745514f
#define W4 0.5f
#define W5 0.6913417161825449f
#define W6 0.8535533905932737f
#define W7 0.9619397662556434f

// interior coverage: out frames [256, 65280); 116 frames per wave
#define TMIN   256
#define TMAX   65280
#define FPW    116
#define NWAVES 561            // ceil(65024/116)
#define BXI    141            // interior blocks per batch
#define GX     (BXI + 2)      // 143 blocks per batch
#define NBLK   (GX * 32)      // 4576 = 8 * 572 exactly

// edge tiles
#define TILE  1024
#define NW    1048
#define NCA   265
#define NFB   259
#define MSTR  265
#define FSTR  17
#define FSTEP (FSTR - 4)      // OLA j-step

typedef float v2f __attribute__((ext_vector_type(2)));
typedef float v4f __attribute__((ext_vector_type(4)));

static __device__ __forceinline__ v2f mk(float a, float b){ v2f r; r.x=a; r.y=b; return r; }
static __device__ __forceinline__ v2f sp(float c){ v2f r; r.x=c; r.y=c; return r; }
static __device__ __forceinline__ v2f vfma(v2f a, v2f b, v2f c){ return __builtin_elementwise_fma(a,b,c); }
static __device__ __forceinline__ v2f vfma(float a, v2f b, v2f c){ return __builtin_elementwise_fma(sp(a),b,c); }

// DPP wavefront shifts (gfx9/CDNA): WF_SL1=0x130 -> lane i reads lane i+1,
// WF_SR1=0x138 -> lane i reads lane i-1. bound_ctrl=0 + old=src: boundary
// lanes keep their own value (outputs of lanes 0..2 / 61..63 are masked off).
static __device__ __forceinline__ float SHP(float x){  // == __shfl(x, lane+1)
  int xi = __builtin_bit_cast(int, x);
  int r = __builtin_amdgcn_update_dpp(xi, xi, 0x130, 0xF, 0xF, false);
  return __builtin_bit_cast(float, r);
}
static __device__ __forceinline__ float SHM(float x){  // == __shfl(x, lane-1)
  int xi = __builtin_bit_cast(int, x);
  int r = __builtin_amdgcn_update_dpp(xi, xi, 0x138, 0xF, 0xF, false);
  return __builtin_bit_cast(float, r);
}

static __device__ __forceinline__ void phase1(float m, float Sr, float Si,
                                              float& pr, float& pi){
  float r2 = fmaf(Sr,Sr, Si*Si);
  if (r2 > 0.f) {
    float rin = __builtin_amdgcn_rsqf(r2);
    float mr = m * rin;
    pr = mr * Sr; pi = mr * Si;
  } else { pr = m; pi = 0.f; }
}
static __device__ __forceinline__ void phasev(v2f m, v2f Sr, v2f Si, v2f& pr, v2f& pi){
  float prx, pix, pry, piy;
  phase1(m.x, Sr.x, Si.x, prx, pix);
  phase1(m.y, Sr.y, Si.y, pry, piy);
  pr = mk(prx, pry); pi = mk(pix, piy);
}

__device__ __constant__ float W2C[16] = {
  0.f, W1*W1, W2*W2, W3*W3, 0.25f, W5*W5, W6*W6, W7*W7,
  1.f, W7*W7, W6*W6, W5*W5, 0.25f, W3*W3, W2*W2, W1*W1 };

__global__ __launch_bounds__(256, 5) void istft_all(
    const float* __restrict__ mag, float* __restrict__ out)
{
  // edge-path LDS (unused by interior blocks). 31752 B -> 5 blocks/CU.
  __shared__ float s_mag[KB * MSTR];
  __shared__ float s_fab[NCA * FSTR];
  __shared__ float s_wav[NW];

  const int tid = threadIdx.x;

  // XCD-chunked bijective swizzle. Dispatch linear id round-robins
  // across 8 XCDs; remap so each XCD owns 572 consecutive tiles (= 4 full
  // batches). Adjacent tiles (shared halo) then share an XCD L2.
  const unsigned lin = (unsigned)blockIdx.y * GX + blockIdx.x;  // 0..4575
  const unsigned swz = (lin & 7u) * (NBLK / 8u) + (lin >> 3);   // bijective
  const unsigned b   = swz / (unsigned)GX;                      // batch
  const int      pos = (int)(swz - b * GX);                     // 0..142

  const float* magb = mag + (size_t)b * (size_t)(KB * TFR);
  float* outb = out + (size_t)b * LW;

  if (pos >= 2) {
    // ---------------- interior: 1 lane = 2 frames, DPP halo ----------------
    const int lane = tid & 63;
    const int wv   = (pos - 2) * 4 + (tid >> 6);
    if (wv >= NWAVES) return;
    const int T0 = TMIN + wv * FPW;
    const int ta = T0 - 6 + 2 * lane;       // even; lane's frame pair (ta, ta+1)

    // mag columns (ta, ta+1) for 9 bins: float2 loads, coalesced
    v2f R0 = *(const v2f*)(magb + 0*TFR + ta);
    v2f R1 = *(const v2f*)(magb + 1*TFR + ta);
    v2f R2 = *(const v2f*)(magb + 2*TFR + ta);
    v2f R3 = *(const v2f*)(magb + 3*TFR + ta);
    v2f R4 = *(const v2f*)(magb + 4*TFR + ta);
    v2f R5 = *(const v2f*)(magb + 5*TFR + ta);
    v2f R6 = *(const v2f*)(magb + 6*TFR + ta);
    v2f R7 = *(const v2f*)(magb + 7*TFR + ta);
    v2f R8 = *(const v2f*)(magb + 8*TFR + ta);

    // ---- stage A: irfft16 of real spectrum, windowed (symmetric frame) ----
    v2f f1,f2,f3,f4,f5,f6,f7,f8;
    {
      v2f p1=R1+R7, m1=R1-R7, p2=R2+R6, m2=R2-R6, p3=R3+R5, m3=R3-R5;
      v2f tp=R0+R8, tm=R0-R8, d13=p1-p3;
      v2f E1 = vfma(2.f, vfma(C1f,m1, vfma(C2f,m2, sp(C3f)*m3)), tm);
      v2f E2 = vfma(2.f, vfma(C2f,d13, -R4), tp);
      v2f E3 = vfma(2.f, vfma(C3f,m1, vfma(-C2f,m2, sp(-C1f)*m3)), tm);
      v2f E4 = vfma(2.f, R4-p2, tp);
      v2f E5 = vfma(2.f, vfma(-C3f,m1, vfma(-C2f,m2, sp(C1f)*m3)), tm);
      v2f E6 = vfma(-2.f, vfma(C2f,d13, R4), tp);
      v2f E7 = vfma(2.f, vfma(-C1f,m1, vfma(C2f,m2, sp(-C3f)*m3)), tm);
      v2f E8 = vfma(2.f, ((p2+R4)-(p1+p3)), tp);
      f1=sp(W1)*E1; f2=sp(W2)*E2; f3=sp(W3)*E3; f4=sp(W4)*E4;
      f5=sp(W5)*E5; f6=sp(W6)*E6; f7=sp(W7)*E7; f8=E8;
    }

    // ---- stage A2: OLA -> wav chunks wc[r] = wav[4t+r] pair ----
    v2f wc0, wc1, wc2, wc3;
    {
      float s4 = SHP(f4.x), s5 = SHP(f5.x), s6 = SHP(f6.x), s7 = SHP(f7.x);
      float a1x = SHP(f1.x), a1y = SHP(f1.y);
      float a2x = SHP(f2.x), a2y = SHP(f2.y);
      float a3x = SHP(f3.x), a3y = SHP(f3.y);
      float m1y = SHM(f1.y), m2y = SHM(f2.y), m3y = SHM(f3.y), m4y = SHM(f4.y);
      v2f f4p1 = mk(f4.y, s4), f5p1 = mk(f5.y, s5), f6p1 = mk(f6.y, s6), f7p1 = mk(f7.y, s7);
      v2f f1p2 = mk(a1x, a1y), f2p2 = mk(a2x, a2y), f3p2 = mk(a3x, a3y);
      v2f f1m1 = mk(m1y, f1.x), f2m1 = mk(m2y, f2.x), f3m1 = mk(m3y, f3.x), f4m1 = mk(m4y, f4.x);
      const v2f inv24 = sp(1.f/24.f);
      wc0 = (f4p1 + f8 + f4m1) * inv24;
      wc1 = (f1p2 + f5p1 + f7 + f3m1) * inv24;
      wc2 = (f2p2 + f6p1 + f6 + f2m1) * inv24;
      wc3 = (f3p2 + f7p1 + f5 + f1m1) * inv24;
    }

    // ---- stage B gather: xs[n] = wav[4t-8+n] pairs ----
    v2f x1,x2,x3,x4,x5,x6,x7,x8w,x9,x10,x11,x12,x13,x14,x15;
    {
      float aw0y = SHM(wc0.y);
      float aw1x = SHM(wc1.x), aw1y = SHM(wc1.y);
      float aw2x = SHM(wc2.x), aw2y = SHM(wc2.y);
      float aw3x = SHM(wc3.x), aw3y = SHM(wc3.y);
      float pw0x = SHP(wc0.x), pw1x = SHP(wc1.x), pw2x = SHP(wc2.x), pw3x = SHP(wc3.x);
      x1  = mk(aw1x, aw1y); x2  = mk(aw2x, aw2y); x3  = mk(aw3x, aw3y);
      x4  = mk(aw0y, wc0.x); x5 = mk(aw1y, wc1.x); x6 = mk(aw2y, wc2.x); x7 = mk(aw3y, wc3.x);
      x8w = wc0; x9 = wc1; x10 = wc2; x11 = wc3;
      x12 = mk(wc0.y, pw0x); x13 = mk(wc1.y, pw1x); x14 = mk(wc2.y, pw2x); x15 = mk(wc3.y, pw3x);
    }
    // window (w0=0 kills tap 0; w8=1)
    x1=sp(W1)*x1; x2=sp(W2)*x2; x3=sp(W3)*x3; x4=sp(W4)*x4; x5=sp(W5)*x5;
    x6=sp(W6)*x6; x7=sp(W7)*x7; x9=sp(W7)*x9; x10=sp(W6)*x10; x11=sp(W5)*x11;
    x12=sp(W4)*x12; x13=sp(W3)*x13; x14=sp(W2)*x14; x15=sp(W1)*x15;

    v2f fc1,fc2,fc3,fc4,fc5,fc6,fc7,fc8,fc9,fc10,fc11,fc12,fc13,fc14,fc15;
    {
      v2f u1=x1+x15, vv1=x1-x15, u2=x2+x14, vv2=x2-x14, u3=x3+x13, vv3=x3-x13,
          u4=x4+x12, vv4=x4-x12, u5=x5+x11, vv5=x5-x11, u6=x6+x10, vv6=x6-x10,
          u7=x7+x9,  vv7=x7-x9;
      v2f P1=u1+u7, M1=u1-u7, P2=u2+u6, M2=u2-u6, P3=u3+u5, M3=u3-u5;
      v2f D13 = P1-P3;
      v2f Sr0 = x8w + ((P1+P2)+(P3+u4));
      v2f Sr1 = vfma(C1f,M1, vfma(C2f,M2, sp(C3f)*M3)) - x8w;
      v2f Sr2 = vfma(C2f,D13, x8w - u4);
      v2f Sr3 = vfma(C3f,M1, vfma(-C2f,M2, sp(-C1f)*M3)) - x8w;
      v2f Sr4 = (u4 - P2) + x8w;
      v2f Sr5 = vfma(-C3f,M1, vfma(-C2f,M2, sp(C1f)*M3)) - x8w;
      v2f Sr6 = vfma(-C2f,D13, x8w - u4);
      v2f Sr7 = vfma(-C1f,M1, vfma(C2f,M2, sp(-C3f)*M3)) - x8w;
      v2f Sr8 = x8w + ((P2+u4)-(P1+P3));
      v2f Q1=vv1+vv7, N1=vv1-vv7, Q2=vv2+vv6, N2=vv2-vv6, Q3=vv3+vv5, N3=vv3-vv5;
      v2f NN = N1+N3;
      v2f Si1 = -(vfma(C3f,Q1, vfma(C2f,Q2, sp(C1f)*Q3)) + vv4);
      v2f Si2 = -vfma(C2f,NN, N2);
      v2f Si3 = -(vfma(C1f,Q1, vfma(C2f,Q2, sp(-C3f)*Q3)) - vv4);
      v2f Si4 = N3 - N1;
      v2f Si5 = -(vfma(C1f,Q1, vfma(-C2f,Q2, sp(-C3f)*Q3)) + vv4);
      v2f Si6 = vfma(-C2f,NN, N2);
      v2f Si7 = -(vfma(C3f,Q1, vfma(-C2f,Q2, sp(C1f)*Q3)) - vv4);

      // phase recombine
      v2f pr0,pr1,pr2,pr3,pr4,pr5,pr6,pr7,pr8;
      v2f pi1,pi2,pi3,pi4,pi5,pi6,pi7;
      pr0 = mk((Sr0.x >= 0.f) ? R0.x : -R0.x,
               (Sr0.y >= 0.f) ? R0.y : -R0.y);
      phasev(R1, Sr1, Si1, pr1, pi1);
      phasev(R2, Sr2, Si2, pr2, pi2);
      phasev(R3, Sr3, Si3, pr3, pi3);
      phasev(R4, Sr4, Si4, pr4, pi4);
      phasev(R5, Sr5, Si5, pr5, pi5);
      phasev(R6, Sr6, Si6, pr6, pi6);
      phasev(R7, Sr7, Si7, pr7, pi7);
      pr8 = mk((Sr8.x >= 0.f) ? R8.x : -R8.x,
               (Sr8.y >= 0.f) ? R8.y : -R8.y);

      // irfft16 of (pr + i*pi), windowed
      v2f ap1=pr1+pr7, bm1=pr1-pr7, ap2=pr2+pr6, bm2=pr2-pr6, ap3=pr3+pr5, bm3=pr3-pr5;
      v2f tp=pr0+pr8, tm=pr0-pr8, ed=ap1-ap3;
      v2f E1 = vfma(2.f, vfma(C1f,bm1, vfma(C2f,bm2, sp(C3f)*bm3)), tm);
      v2f E2 = vfma(2.f, vfma(C2f,ed, -pr4), tp);
      v2f E3 = vfma(2.f, vfma(C3f,bm1, vfma(-C2f,bm2, sp(-C1f)*bm3)), tm);
      v2f E4 = vfma(2.f, pr4-ap2, tp);
      v2f E5 = vfma(2.f, vfma(-C3f,bm1, vfma(-C2f,bm2, sp(C1f)*bm3)), tm);
      v2f E6 = vfma(-2.f, vfma(C2f,ed, pr4), tp);
      v2f E7 = vfma(2.f, vfma(-C1f,bm1, vfma(C2f,bm2, sp(-C3f)*bm3)), tm);
      v2f E8 = vfma(2.f, ((ap2+pr4)-(ap1+ap3)), tp);
      v2f q1=pi1+pi7, n1=pi1-pi7, q2=pi2+pi6, n2=pi2-pi6, q3=pi3+pi5, n3=pi3-pi5;
      v2f nn = n1+n3;
      v2f O1 = sp(-2.f)*(vfma(C3f,q1, vfma(C2f,q2, sp(C1f)*q3)) + pi4);
      v2f O2 = sp(-2.f)*vfma(C2f,nn, n2);
      v2f O3 = sp(-2.f)*(vfma(C1f,q1, vfma(C2f,q2, sp(-C3f)*q3)) - pi4);
      v2f O4 = sp(-2.f)*(n1-n3);
      v2f O5 = sp(-2.f)*(vfma(C1f,q1, vfma(-C2f,q2, sp(-C3f)*q3)) + pi4);
      v2f O6 = sp(-2.f)*vfma(C2f,nn, -n2);
      v2f O7 = sp(-2.f)*(vfma(C3f,q1, vfma(-C2f,q2, sp(C1f)*q3)) - pi4);

      fc1 = sp(W1)*(E1+O1); fc2 = sp(W2)*(E2+O2); fc3 = sp(W3)*(E3+O3); fc4 = sp(W4)*(E4+O4);
      fc5 = sp(W5)*(E5+O5); fc6 = sp(W6)*(E6+O6); fc7 = sp(W7)*(E7+O7); fc8 = E8;
      fc9  = sp(W7)*(E7-O7); fc10 = sp(W6)*(E6-O6); fc11 = sp(W5)*(E5-O5); fc12 = sp(W4)*(E4-O4);
      fc13 = sp(W3)*(E3-O3); fc14 = sp(W2)*(E2-O2); fc15 = sp(W1)*(E1-O1);
    }

    // ---- stage C: final OLA -> out[4ta .. 4ta+7] ----
    {
      float c1x = SHP(fc1.x), c1y = SHP(fc1.y);
      float c2x = SHP(fc2.x), c2y = SHP(fc2.y);
      float c3x = SHP(fc3.x), c3y = SHP(fc3.y);
      float c4x = SHP(fc4.x), c5x = SHP(fc5.x), c6x = SHP(fc6.x), c7x = SHP(fc7.x);
      float d12 = SHM(fc12.y), d13s = SHM(fc13.y), d14 = SHM(fc14.y), d15 = SHM(fc15.y);
      v2f g1 = mk(c1x, c1y), g2 = mk(c2x, c2y), g3 = mk(c3x, c3y);
      v2f h4 = mk(fc4.y, c4x), h5 = mk(fc5.y, c5x), h6 = mk(fc6.y, c6x), h7 = mk(fc7.y, c7x);
      v2f q12 = mk(d12, fc12.x), q13 = mk(d13s, fc13.x), q14 = mk(d14, fc14.x), q15 = mk(d15, fc15.x);
      const v2f inv24 = sp(1.f/24.f);
      v2f o0 = (h4 + fc8  + q12) * inv24;
      v2f o1 = (g1 + h5 + fc9  + q13) * inv24;
      v2f o2 = (g2 + h6 + fc10 + q14) * inv24;
      v2f o3 = (g3 + h7 + fc11 + q15) * inv24;
      if (lane >= 3 && lane <= 60 && ta < TMAX) {
        v4f s0 = {o0.x, o1.x, o2.x, o3.x};
        v4f s1 = {o0.y, o1.y, o2.y, o3.y};
        __builtin_nontemporal_store(s0, (v4f*)(outb + 4*(size_t)ta));
        __builtin_nontemporal_store(s1, (v4f*)(outb + 4*(size_t)ta + 4));
      }
    }
    return;
  }

  // ---------------- edge blocks: validated LDS pipeline ----------------
  const int l0  = (pos == 0) ? 0 : 261120;
  const int t4  = l0 >> 2;
  const int tAlo = t4 - 4;
  const int tBlo = t4 - 1;
  const int wbase = l0 - 12;

#pragma unroll
  for (int k = 0; k < KB; ++k) {
    const float* mrow = magb + (size_t)k * TFR + tAlo;
    for (int c = tid; c < NCA; c += 256) {
      int t = tAlo + c;
      s_mag[k * MSTR + c] = ((unsigned)t < (unsigned)TFR) ? mrow[c] : 0.f;
    }
  }
  __syncthreads();

  for (int f = tid; f < NCA; f += 256) {
    float R0 = s_mag[0*MSTR+f], R1 = s_mag[1*MSTR+f], R2 = s_mag[2*MSTR+f],
          R3 = s_mag[3*MSTR+f], R4 = s_mag[4*MSTR+f], R5 = s_mag[5*MSTR+f],
          R6 = s_mag[6*MSTR+f], R7 = s_mag[7*MSTR+f], R8 = s_mag[8*MSTR+f];
    float p1=R1+R7, m1=R1-R7, p2=R2+R6, m2=R2-R6, p3=R3+R5, m3=R3-R5;
    float tp=R0+R8, tm=R0-R8, d13=p1-p3;
    float E1 = fmaf(2.f, fmaf(C1f,m1, fmaf(C2f,m2, C3f*m3)), tm);
    float E2 = fmaf(2.f, fmaf(C2f,d13, -R4), tp);
    float E3 = fmaf(2.f, fmaf(C3f,m1, fmaf(-C2f,m2, -C1f*m3)), tm);
    float E4 = fmaf(2.f, R4-p2, tp);
    float E5 = fmaf(2.f, fmaf(-C3f,m1, fmaf(-C2f,m2, C1f*m3)), tm);
    float E6 = fmaf(-2.f, fmaf(C2f,d13, R4), tp);
    float E7 = fmaf(2.f, fmaf(-C1f,m1, fmaf(C2f,m2, -C3f*m3)), tm);
    float E8 = fmaf(2.f, ((p2+R4)-(p1+p3)), tp);
    float* rp = s_fab + f * FSTR;
    rp[0]=0.f;    rp[1]=W1*E1;  rp[2]=W2*E2;  rp[3]=W3*E3;
    rp[4]=W4*E4;  rp[5]=W5*E5;  rp[6]=W6*E6;  rp[7]=W7*E7;
    rp[8]=E8;     rp[9]=W7*E7;  rp[10]=W6*E6; rp[11]=W5*E5;
    rp[12]=W4*E4; rp[13]=W3*E3; rp[14]=W2*E2; rp[15]=W1*E1;
  }
  __syncthreads();

  for (int i = tid; i < NW; i += 256) {
    int m = wbase + i;
    float val = 0.f;
    if (m >= 0 && m < LW) {
      int q = m + 8;
      int tq = q >> 2, r = q & 3;
      int base = (tq - tAlo) * FSTR + r;
      float acc = 0.f, env = 0.f;
#pragma unroll
      for (int j = 0; j < 4; ++j) {
        int t = tq - j;
        if ((unsigned)t < (unsigned)TFR) { acc += s_fab[base - FSTEP*j]; env += W2C[r + 4*j]; }
      }
      val = acc * __builtin_amdgcn_rcpf(16.f * env);
    }
    s_wav[i] = val;
  }
  __syncthreads();

  for (int f = tid; f < NFB; f += 256) {
    float* rp = s_fab + f * FSTR;
    int t2 = tBlo + f;
    bool valid = ((unsigned)t2 < (unsigned)TFR);
    if (valid) {
      float xs[16];
      int g0 = 4*t2 - 8;
#pragma unroll
      for (int n = 0; n < 16; ++n) {
        int g = g0 + n;
        g = (g < 0) ? -g : g;
        g = (g < LW) ? g : (2*(LW-1) - g);
        xs[n] = s_wav[g - wbase];
      }
      float x1=xs[1]*W1, x2=xs[2]*W2, x3=xs[3]*W3, x4=xs[4]*W4, x5=xs[5]*W5,
            x6=xs[6]*W6, x7=xs[7]*W7, x8w=xs[8], x9=xs[9]*W7, x10=xs[10]*W6,
            x11=xs[11]*W5, x12=xs[12]*W4, x13=xs[13]*W3, x14=xs[14]*W2, x15=xs[15]*W1;
      float u1=x1+x15, v1=x1-x15, u2=x2+x14, v2=x2-x14, u3=x3+x13, v3=x3-x13,
            u4=x4+x12, v4=x4-x12, u5=x5+x11, v5=x5-x11, u6=x6+x10, v6=x6-x10,
            u7=x7+x9,  v7=x7-x9;
      float P1=u1+u7, M1=u1-u7, P2=u2+u6, M2=u2-u6, P3=u3+u5, M3=u3-u5;
      float D13 = P1-P3;
      float Sr0 = x8w + ((P1+P2)+(P3+u4));
      float Sr1 = fmaf(C1f,M1, fmaf(C2f,M2, C3f*M3)) - x8w;
      float Sr2 = fmaf(C2f,D13, x8w - u4);
      float Sr3 = fmaf(C3f,M1, fmaf(-C2f,M2, -C1f*M3)) - x8w;
      float Sr4 = (u4 - P2) + x8w;
      float Sr5 = fmaf(-C3f,M1, fmaf(-C2f,M2, C1f*M3)) - x8w;
      float Sr6 = fmaf(-C2f,D13, x8w - u4);
      float Sr7 = fmaf(-C1f,M1, fmaf(C2f,M2, -C3f*M3)) - x8w;
      float Sr8 = x8w + ((P2+u4)-(P1+P3));
      float Q1=v1+v7, N1=v1-v7, Q2=v2+v6, N2=v2-v6, Q3=v3+v5, N3=v3-v5;
      float NN = N1+N3;
      float Si1 = -(fmaf(C3f,Q1, fmaf(C2f,Q2, C1f*Q3)) + v4);
      float Si2 = -fmaf(C2f,NN, N2);
      float Si3 = -(fmaf(C1f,Q1, fmaf(C2f,Q2, -C3f*Q3)) - v4);
      float Si4 = N3 - N1;
      float Si5 = -(fmaf(C1f,Q1, fmaf(-C2f,Q2, -C3f*Q3)) + v4);
      float Si6 = fmaf(-C2f,NN, N2);
      float Si7 = -(fmaf(C3f,Q1, fmaf(-C2f,Q2, C1f*Q3)) - v4);

      const float* mcol = s_mag + (f + 3);
      float pr0,pr1,pr2,pr3,pr4,pr5,pr6,pr7,pr8;
      float pi1,pi2,pi3,pi4,pi5,pi6,pi7;
      { float mm = mcol[0];
        pr0 = (Sr0 >= 0.f) ? mm : -mm; }
      phase1(mcol[1*MSTR], Sr1, Si1, pr1, pi1);
      phase1(mcol[2*MSTR], Sr2, Si2, pr2, pi2);
      phase1(mcol[3*MSTR], Sr3, Si3, pr3, pi3);
      phase1(mcol[4*MSTR], Sr4, Si4, pr4, pi4);
      phase1(mcol[5*MSTR], Sr5, Si5, pr5, pi5);
      phase1(mcol[6*MSTR], Sr6, Si6, pr6, pi6);
      phase1(mcol[7*MSTR], Sr7, Si7, pr7, pi7);
      { float mm = mcol[8*MSTR];
        pr8 = (Sr8 >= 0.f) ? mm : -mm; }

      float ap1=pr1+pr7, bm1=pr1-pr7, ap2=pr2+pr6, bm2=pr2-pr6, ap3=pr3+pr5, bm3=pr3-pr5;
      float tp=pr0+pr8, tm=pr0-pr8, ed=ap1-ap3;
      float E1 = fmaf(2.f, fmaf(C1f,bm1, fmaf(C2f,bm2, C3f*bm3)), tm);
      float E2 = fmaf(2.f, fmaf(C2f,ed, -pr4), tp);
      float E3 = fmaf(2.f, fmaf(C3f,bm1, fmaf(-C2f,bm2, -C1f*bm3)), tm);
      float E4 = fmaf(2.f, pr4-ap2, tp);
      float E5 = fmaf(2.f, fmaf(-C3f,bm1, fmaf(-C2f,bm2, C1f*bm3)), tm);
      float E6 = fmaf(-2.f, fmaf(C2f,ed, pr4), tp);
      float E7 = fmaf(2.f, fmaf(-C1f,bm1, fmaf(C2f,bm2, -C3f*bm3)), tm);
      float E8 = fmaf(2.f, ((ap2+pr4)-(ap1+ap3)), tp);
      float q1=pi1+pi7, n1=pi1-pi7, q2=pi2+pi6, n2=pi2-pi6, q3=pi3+pi5, n3=pi3-pi5;
      float nn = n1+n3;
      float O1 = -2.f*(fmaf(C3f,q1, fmaf(C2f,q2, C1f*q3)) + pi4);
      float O2 = -2.f*fmaf(C2f,nn, n2);
      float O3 = -2.f*(fmaf(C1f,q1, fmaf(C2f,q2, -C3f*q3)) - pi4);
      float O4 = -2.f*(n1-n3);
      float O5 = -2.f*(fmaf(C1f,q1, fmaf(-C2f,q2, -C3f*q3)) + pi4);
      float O6 = -2.f*fmaf(C2f,nn, -n2);
      float O7 = -2.f*(fmaf(C3f,q1, fmaf(-C2f,q2, C1f*q3)) - pi4);

      rp[0]=0.f;          rp[1]=W1*(E1+O1);  rp[2]=W2*(E2+O2);  rp[3]=W3*(E3+O3);
      rp[4]=W4*(E4+O4);   rp[5]=W5*(E5+O5);  rp[6]=W6*(E6+O6);  rp[7]=W7*(E7+O7);
      rp[8]=E8;           rp[9]=W7*(E7-O7);  rp[10]=W6*(E6-O6); rp[11]=W5*(E5-O5);
      rp[12]=W4*(E4-O4);  rp[13]=W3*(E3-O3); rp[14]=W2*(E2-O2); rp[15]=W1*(E1-O1);
    } else {
#pragma unroll
      for (int n = 0; n < 16; ++n) rp[n] = 0.f;
    }
  }
  __syncthreads();

  for (int i = tid; i < TILE; i += 256) {
    int l = l0 + i;
    if (l < LW) {
      int q = l + 8;
      int tq = q >> 2, r = q & 3;
      int base = (tq - tBlo) * FSTR + r;
      float acc = 0.f, env = 0.f;
#pragma unroll
      for (int j = 0; j < 4; ++j) {
        int t = tq - j;
        if ((unsigned)t < (unsigned)TFR) { acc += s_fab[base - FSTEP*j]; env += W2C[r + 4*j]; }
      }
      __builtin_nontemporal_store(acc * __builtin_amdgcn_rcpf(16.f * env), &outb[l]);
    }
  }
}

extern "C" void kernel_launch(void* const* d_in, const int* in_sizes, int n_in,
                              void* d_out, int out_size, void* d_ws, size_t ws_size,
                              hipStream_t stream) {
  const float* mag = (const float*)d_in[0];   // (32, 9, 65536) f32
  float* out = (float*)d_out;                 // (32, 262140) f32
  dim3 grid(GX, 32);                          // 143 blocks/batch (2 edge + 141 interior)
  istft_all<<<grid, 256, 0, stream>>>(mag, out);
}